// Round 2
// baseline (569.881 us; speedup 1.0000x reference)
//
#include <hip/hip_runtime.h>
#include <math.h>

#define T_DIM 2048
#define S_DIM 2048
#define D_DIM 64
#define BH_DIM 32
#define U_SEL 614
#define LOG_S_D 7.624618986159398
#define LOG2E_F 1.4426950408889634f
#define LN2_D 0.6931471805599453
#define SCL_Q (0.125f * LOG2E_F)  // q scale folded with log2e: scores in log2 domain

typedef __attribute__((ext_vector_type(8))) short bf16x8;
typedef __attribute__((ext_vector_type(4))) short bf16x4;
typedef __attribute__((ext_vector_type(4))) float f32x4;
typedef __attribute__((ext_vector_type(4))) int i32x4;

__device__ __forceinline__ unsigned short bf16_rne(float x) {
  unsigned u = __float_as_uint(x);
  u += 0x7FFF + ((u >> 16) & 1);
  return (unsigned short)(u >> 16);
}
__device__ __forceinline__ float bf16_to_f(unsigned short h) {
  return __uint_as_float(((unsigned)h) << 16);
}
__device__ __forceinline__ int cvt_pk_bf16(float lo, float hi) {
  int r;
  asm("v_cvt_pk_bf16_f32 %0, %1, %2" : "=v"(r) : "v"(lo), "v"(hi));
  return r;
}

#define GLD_LDS16(g, l)                                                        \
  __builtin_amdgcn_global_load_lds(                                            \
      (const __attribute__((address_space(1))) unsigned int*)(const void*)(g), \
      (__attribute__((address_space(3))) unsigned int*)(void*)(l), 16, 0, 0)

// stage 16 KB image: 4 waves x 4 instr x 64 lanes x 16 B
__device__ __forceinline__ void stage_img16(const unsigned short* __restrict__ g,
                                            unsigned short* l, int lane, int w) {
#pragma unroll
  for (int it = 0; it < 4; ++it) {
    const int chunk = it * 4 + w;
    GLD_LDS16((const char*)g + chunk * 1024 + lane * 16, (char*)l + chunk * 1024);
  }
}

// swizzled image, 64-wide rows: element (r,d) at r*64 + ((d>>3)^(r&7))*8 + (d&7)
__device__ __forceinline__ bf16x8 ldfrag_sw(const unsigned short* buf, int row, int chunk) {
  return *(const bf16x8*)(buf + (row << 6) + (((chunk) ^ (row & 7)) << 3));
}
// two stacked 64-row images (rows 0..127)
__device__ __forceinline__ bf16x8 ldfrag_k128(const unsigned short* buf, int row, int chunk) {
  return *(const bf16x8*)(buf + ((row >> 6) << 12) + ((row & 63) << 6) +
                          (((chunk) ^ (row & 7)) << 3));
}

// ====== convert: K -> 64-row tiles [hi 8KB | lo 8KB] swizzled; V -> V^T images; zero(out,zacc) ======
__global__ __launch_bounds__(256) void convert_kernel(
    const float* __restrict__ kin, const float* __restrict__ vin,
    unsigned short* __restrict__ kimg, unsigned short* __restrict__ vt_g,
    float* __restrict__ out, float* __restrict__ zacc) {
  __shared__ float vld[128][65];
  const int jb = blockIdx.x;
  const int tid = threadIdx.x;
  if (jb < 1024) {  // K: 32 bh x 32 tiles of 64 rows
    const int bh = jb >> 5, tl = jb & 31;
    const float* src = kin + ((size_t)bh * 2048 + tl * 64) * 64;
    unsigned short* dst = kimg + (size_t)(bh * 32 + tl) * 8192;
#pragma unroll
    for (int g = 0; g < 2; ++g) {
      const int flat = g * 256 + tid;  // 512 chunks = 64 rows x 8
      const int r = flat >> 3, c = flat & 7;
      const float4 f0 = *(const float4*)(src + r * 64 + c * 8);
      const float4 f1 = *(const float4*)(src + r * 64 + c * 8 + 4);
      const float xs[8] = {f0.x, f0.y, f0.z, f0.w, f1.x, f1.y, f1.z, f1.w};
      bf16x8 hv, lv;
#pragma unroll
      for (int j = 0; j < 8; ++j) {
        const unsigned short h = bf16_rne(xs[j]);
        hv[j] = (short)h;
        lv[j] = (short)bf16_rne(xs[j] - bf16_to_f(h));
      }
      const int base = (r << 6) + ((c ^ (r & 7)) << 3);
      *(bf16x8*)(dst + base) = hv;
      *(bf16x8*)(dst + 4096 + base) = lv;
    }
  } else if (jb < 1536) {  // V^T: [64 d][128 s] bf16, chunk ^ (d&15)
    const int jv = jb - 1024;
    const int bh = jv >> 4, tl = jv & 15;
    const float* src = vin + ((size_t)bh * 2048 + tl * 128) * 64;
#pragma unroll
    for (int g = 0; g < 8; ++g) {
      const int f = g * 256 + tid;
      const int r = f >> 4, c4 = f & 15;
      const float4 x = *(const float4*)(src + r * 64 + c4 * 4);
      vld[r][c4 * 4 + 0] = x.x;
      vld[r][c4 * 4 + 1] = x.y;
      vld[r][c4 * 4 + 2] = x.z;
      vld[r][c4 * 4 + 3] = x.w;
    }
    __syncthreads();
    unsigned short* dst = vt_g + (size_t)(bh * 16 + tl) * 8192;
#pragma unroll
    for (int g = 0; g < 4; ++g) {
      const int oc = g * 256 + tid;
      const int d = oc >> 4, cc = oc & 15;
      bf16x8 hv;
#pragma unroll
      for (int j = 0; j < 8; ++j) hv[j] = (short)bf16_rne(vld[cc * 8 + j][d]);
      *(bf16x8*)(dst + (d << 7) + (((cc ^ (d & 15))) << 3)) = hv;
    }
  } else if (jb < 2048) {  // zero d_out: 512 blocks x 2048 float4
    float4* o4 = (float4*)out;
    const size_t b = (size_t)(jb - 1536);
#pragma unroll
    for (int g = 0; g < 8; ++g)
      o4[b * 2048 + g * 256 + tid] = make_float4(0.f, 0.f, 0.f, 0.f);
  } else {  // zero zacc region: 3 blocks x 2048 float4
    float4* z4 = (float4*)zacc;
    const size_t b = (size_t)(jb - 2048);
#pragma unroll
    for (int g = 0; g < 8; ++g)
      z4[b * 2048 + g * 256 + tid] = make_float4(0.f, 0.f, 0.f, 0.f);
  }
}

// ====== Phase A: partial (Z,W) per (t-row, s-half), bf16x3 MFMA, BK=64 dbuf ======
// grid 1024: bh = b&31 (XCD-local), ttile = (b>>5)&15, shalf = b>>9
__global__ __launch_bounds__(256, 4) void kl_score_mfma(
    const float* __restrict__ q, const unsigned short* __restrict__ kimg,
    float2* __restrict__ zw) {
  __shared__ __align__(16) unsigned short lbuf[2][8192];  // 2 x 16 KB
  const int b = blockIdx.x;
  const int bh = b & 31;
  const int t0 = ((b >> 5) & 15) * 128;
  const int shalf = b >> 9;
  const int tid = threadIdx.x;
  const int lane = tid & 63, w = tid >> 6, quad = lane >> 4, l15 = lane & 15;
  const float* qb = q + (size_t)bh * (2048 * 64) + (size_t)t0 * 64;
  const unsigned short* kb = kimg + (size_t)bh * (32 * 8192);
  const int tg0 = shalf * 16;

  {  // q tile -> hi image in lbuf[0], lo image in lbuf[1] (scaled by 0.125*log2e)
#pragma unroll
    for (int g = 0; g < 4; ++g) {
      const int flat = g * 256 + tid;  // 1024 chunks = 128 rows x 8
      const int r = flat >> 3, c = flat & 7;
      const float4 f0 = *(const float4*)(qb + r * 64 + c * 8);
      const float4 f1 = *(const float4*)(qb + r * 64 + c * 8 + 4);
      const float xs[8] = {f0.x, f0.y, f0.z, f0.w, f1.x, f1.y, f1.z, f1.w};
      bf16x8 hv, lv;
#pragma unroll
      for (int j = 0; j < 8; ++j) {
        const float x = xs[j] * SCL_Q;
        const unsigned short h = bf16_rne(x);
        hv[j] = (short)h;
        lv[j] = (short)bf16_rne(x - bf16_to_f(h));
      }
      const int r2 = r & 63, hi2 = r >> 6;  // rows 0-63 -> lbuf[x][0..4096), 64-127 -> +4096
      const int base = hi2 * 4096 + (r2 << 6) + ((c ^ (r2 & 7)) << 3);
      *(bf16x8*)(&lbuf[0][0] + base) = hv;
      *(bf16x8*)(&lbuf[1][0] + base) = lv;
    }
  }
  __syncthreads();

  bf16x8 ah[2][2], al[2][2];  // persistent q A-fragments (wave w: t-rows w*32..w*32+31)
#pragma unroll
  for (int rt = 0; rt < 2; ++rt) {
    const int row = w * 32 + rt * 16 + l15;
#pragma unroll
    for (int kc = 0; kc < 2; ++kc) {
      ah[rt][kc] = ldfrag_k128(&lbuf[0][0], row, kc * 4 + quad);
      al[rt][kc] = ldfrag_k128(&lbuf[1][0], row, kc * 4 + quad);
    }
  }
  __syncthreads();

  stage_img16(kb + (size_t)tg0 * 8192, &lbuf[0][0], lane, w);
  __syncthreads();  // drain tile 0

  float Zf[8], Wf[8];
#pragma unroll
  for (int i = 0; i < 8; ++i) { Zf[i] = 0.f; Wf[i] = 0.f; }

  for (int t = 0; t < 16; ++t) {
    if (t < 15)
      stage_img16(kb + (size_t)(tg0 + t + 1) * 8192, &lbuf[(t + 1) & 1][0], lane, w);
    const unsigned short* cb = &lbuf[t & 1][0];  // [hi 4096 | lo 4096] elems, 64 rows

    f32x4 acc[2][4];
#pragma unroll
    for (int rt = 0; rt < 2; ++rt)
#pragma unroll
      for (int ct = 0; ct < 4; ++ct) acc[rt][ct] = (f32x4){0.f, 0.f, 0.f, 0.f};

#pragma unroll
    for (int ct = 0; ct < 4; ++ct) {
      const int srow = ct * 16 + l15;
      const bf16x8 bh0 = ldfrag_sw(cb, srow, quad);
      const bf16x8 bl0 = ldfrag_sw(cb + 4096, srow, quad);
      const bf16x8 bh1 = ldfrag_sw(cb, srow, 4 + quad);
      const bf16x8 bl1 = ldfrag_sw(cb + 4096, srow, 4 + quad);
#pragma unroll
      for (int rt = 0; rt < 2; ++rt) {
        f32x4 c = acc[rt][ct];
        c = __builtin_amdgcn_mfma_f32_16x16x32_bf16(ah[rt][0], bh0, c, 0, 0, 0);
        c = __builtin_amdgcn_mfma_f32_16x16x32_bf16(al[rt][0], bh0, c, 0, 0, 0);
        c = __builtin_amdgcn_mfma_f32_16x16x32_bf16(ah[rt][0], bl0, c, 0, 0, 0);
        c = __builtin_amdgcn_mfma_f32_16x16x32_bf16(ah[rt][1], bh1, c, 0, 0, 0);
        c = __builtin_amdgcn_mfma_f32_16x16x32_bf16(al[rt][1], bh1, c, 0, 0, 0);
        c = __builtin_amdgcn_mfma_f32_16x16x32_bf16(ah[rt][1], bl1, c, 0, 0, 0);
        acc[rt][ct] = c;
      }
    }

    // no-max epilogue (log2 domain): e = 2^t, W2 += e*t  (fp32 accumulators)
#pragma unroll
    for (int rt = 0; rt < 2; ++rt)
#pragma unroll
      for (int r = 0; r < 4; ++r) {
        float zp = 0.f, wp = 0.f;
#pragma unroll
        for (int ct = 0; ct < 4; ++ct) {
          const float tt = acc[rt][ct][r];
          const float e = exp2f(tt);
          zp += e;
          wp = fmaf(e, tt, wp);
        }
        Zf[rt * 4 + r] += zp;
        Wf[rt * 4 + r] += wp;
      }
    __syncthreads();  // readers done; drains prefetch of t+1
  }

#pragma unroll
  for (int i = 0; i < 8; ++i) {
    float Zt = Zf[i], Wt = Wf[i];
#pragma unroll
    for (int mask = 1; mask <= 8; mask <<= 1) {
      Zt += __shfl_xor(Zt, mask);
      Wt += __shfl_xor(Wt, mask);
    }
    if (l15 == 0) {
      const int row = t0 + w * 32 + (i >> 2) * 16 + quad * 4 + (i & 3);
      zw[((size_t)shalf * 32 + bh) * 2048 + row] = make_float2(Zt, Wt);
    }
  }
}

// ====== Phase B: kl from (Z,W) halves + exact top-614, bitonic, 1024 threads ======
__global__ __launch_bounds__(1024) void topk_kernel(const float2* __restrict__ zw,
                                                    int* __restrict__ topk) {
  __shared__ float sv[2048];
  __shared__ int si[2048];
  const int bh = blockIdx.x;
  const int tid = threadIdx.x;
  for (int i = tid; i < 2048; i += 1024) {
    const float2 a = zw[(size_t)bh * 2048 + i];
    const float2 c = zw[(size_t)(32 + bh) * 2048 + i];
    const double Z = (double)a.x + (double)c.x;
    const double W = (double)a.y + (double)c.y;
    sv[i] = (float)(LN2_D * (W / Z) - log(Z) + LOG_S_D);
    si[i] = i;
  }
  __syncthreads();
  for (int kk = 2; kk <= 2048; kk <<= 1) {
    for (int j = kk >> 1; j > 0; j >>= 1) {
      const int p = tid;
      const int i = ((p & ~(j - 1)) << 1) | (p & (j - 1));
      const int pr = i | j;
      const float v1 = sv[i], v2 = sv[pr];
      const int i1 = si[i], i2 = si[pr];
      const bool beforePI = (v2 > v1) || (v2 == v1 && i2 < i1);
      const bool dirDesc = ((i & kk) == 0);
      const bool doSwap = dirDesc ? beforePI : !beforePI;
      if (doSwap) { sv[i] = v2; sv[pr] = v1; si[i] = i2; si[pr] = i1; }
      __syncthreads();
    }
  }
  for (int i = tid; i < U_SEL; i += 1024) topk[bh * U_SEL + i] = si[i];
}

// ====== Phase C: bf16 MFMA attention, all-register K/V/P path, s-split 4-way ======
// Key structure: within a block, wave w exclusively owns s-rows [w*32, w*32+32)
// of each 128-s tile -> K and V fragments are per-lane-contiguous 16B in the
// pre-swizzled global images: load straight to registers (no LDS, no barriers).
// P (QK output -> PV A-operand) is an intra-wave lane remap: cvt_pk_bf16 pack
// + __shfl. LDS only for q staging + output reduction (17.5 KB -> 3 blocks/CU).
struct __align__(16) SmC {
  union { unsigned short qs[64 * 64]; float obuf[64 * 64]; } u;  // 16 KB (qs=8 KB, dead after qf load)
  float zred[4][64];                                             // 1 KB
};

// grid 1280: bh = b&31 (XCD-local), t = b>>5: schunk = t&3 (512 s), l0 = (t>>2)*64
__global__ __launch_bounds__(256, 3) void sparse_attn_mfma(
    const float* __restrict__ q, const unsigned short* __restrict__ kimg,
    const unsigned short* __restrict__ vt_g, const int* __restrict__ topk,
    float* __restrict__ out, float* __restrict__ zacc) {
  __shared__ SmC sm;
  const int b = blockIdx.x;
  const int bh = b & 31;
  const int t = b >> 5;
  const int schunk = t & 3;
  const int l0 = (t >> 2) * 64;
  const int tid = threadIdx.x;
  const int lane = tid & 63, w = tid >> 6, quad = lane >> 4, l15 = lane & 15;
  const float* qb = q + (size_t)bh * (2048 * 64);
  const char* kbB = (const char*)(kimg + (size_t)bh * (32 * 8192));
  const char* vtB = (const char*)(vt_g + (size_t)bh * (16 * 8192));
  const int* tkb = topk + bh * U_SEL;

  {  // gather selected q rows -> bf16 * (0.125*log2e), swizzled image in LDS
#pragma unroll
    for (int g = 0; g < 2; ++g) {
      const int ch = g * 256 + tid;
      const int r = ch >> 3, c = ch & 7;
      const int l = l0 + r;
      const int row = (l < U_SEL) ? tkb[l] : tkb[0];
      const float4 f0 = *(const float4*)(qb + (size_t)row * 64 + c * 8);
      const float4 f1 = *(const float4*)(qb + (size_t)row * 64 + c * 8 + 4);
      const float xs[8] = {f0.x, f0.y, f0.z, f0.w, f1.x, f1.y, f1.z, f1.w};
      bf16x8 hv;
#pragma unroll
      for (int j = 0; j < 8; ++j) hv[j] = (short)bf16_rne(xs[j] * SCL_Q);
      *(bf16x8*)&sm.u.qs[(r << 6) + ((c ^ (r & 7)) << 3)] = hv;
    }
  }
  __syncthreads();

  bf16x8 qf[4][2];  // persistent q B-fragments
#pragma unroll
  for (int nt = 0; nt < 4; ++nt)
#pragma unroll
    for (int kc = 0; kc < 2; ++kc)
      qf[nt][kc] = ldfrag_sw(sm.u.qs, nt * 16 + l15, kc * 4 + quad);

  // per-lane static byte offsets into the swizzled K / V^T global images
  int kq[2][2];
#pragma unroll
  for (int mt = 0; mt < 2; ++mt) {
    const int base = w * 32 + mt * 16;  // row in 128-row K pair
    const int img = base >> 6;          // which 64-row image (0/1)
    const int row64 = (base & 63) + l15;
    kq[mt][0] = img * 16384 + row64 * 128 + ((quad ^ (l15 & 7)) << 4);
    kq[mt][1] = img * 16384 + row64 * 128 + (((4 + quad) ^ (l15 & 7)) << 4);
  }
  int voff[4];
#pragma unroll
  for (int dt = 0; dt < 4; ++dt)
    voff[dt] = (dt * 16 + l15) * 256 + (((w * 4 + quad) ^ l15) << 4);

  const int sl0 = ((quad & 1) << 5) + l15;  // shfl source lanes for P remap
  const int sl1 = sl0 + 16;
  const bool hi2 = quad >= 2;

  float zrun[4] = {0.f, 0.f, 0.f, 0.f};
  f32x4 oacc[4][4];
#pragma unroll
  for (int a = 0; a < 4; ++a)
#pragma unroll
    for (int b2 = 0; b2 < 4; ++b2) oacc[a][b2] = (f32x4){0.f, 0.f, 0.f, 0.f};

  for (int st = 0; st < 4; ++st) {
    const char* kp = kbB + (size_t)(schunk * 4 + st) * 32768;  // 2 K-images / tile
    const char* vp = vtB + (size_t)(schunk * 4 + st) * 16384;  // 1 V^T image / tile

    // K fragments: straight to registers
    const bf16x8 a00 = *(const bf16x8*)(kp + kq[0][0]);
    const bf16x8 a01 = *(const bf16x8*)(kp + kq[0][1]);
    const bf16x8 a10 = *(const bf16x8*)(kp + kq[1][0]);
    const bf16x8 a11 = *(const bf16x8*)(kp + kq[1][1]);

    // S^T = K·q^T : C[m=s][n=qr]; lane holds qr=l15, s-local = mt*16+quad*4+r
    f32x4 sacc[2][4];
#pragma unroll
    for (int mt = 0; mt < 2; ++mt)
#pragma unroll
      for (int nt = 0; nt < 4; ++nt) {
        f32x4 c = (f32x4){0.f, 0.f, 0.f, 0.f};
        c = __builtin_amdgcn_mfma_f32_16x16x32_bf16(mt ? a10 : a00, qf[nt][0], c, 0, 0, 0);
        c = __builtin_amdgcn_mfma_f32_16x16x32_bf16(mt ? a11 : a01, qf[nt][1], c, 0, 0, 0);
        sacc[mt][nt] = c;
      }

    // p = 2^t; pack to bf16 pairs (word k holds s-pair {base+2k, base+2k+1})
    int wd[4][4];
#pragma unroll
    for (int nt = 0; nt < 4; ++nt) {
      const float p0 = exp2f(sacc[0][nt][0]), p1 = exp2f(sacc[0][nt][1]);
      const float p2 = exp2f(sacc[0][nt][2]), p3 = exp2f(sacc[0][nt][3]);
      const float p4 = exp2f(sacc[1][nt][0]), p5 = exp2f(sacc[1][nt][1]);
      const float p6 = exp2f(sacc[1][nt][2]), p7 = exp2f(sacc[1][nt][3]);
      zrun[nt] += (p0 + p1 + p2 + p3) + (p4 + p5 + p6 + p7);
      wd[nt][0] = cvt_pk_bf16(p0, p1);
      wd[nt][1] = cvt_pk_bf16(p2, p3);
      wd[nt][2] = cvt_pk_bf16(p4, p5);
      wd[nt][3] = cvt_pk_bf16(p6, p7);
    }

    // V fragments: straight to registers (latency covered by shfl phase + TLP)
    bf16x8 vbf[4];
#pragma unroll
    for (int dt = 0; dt < 4; ++dt) vbf[dt] = *(const bf16x8*)(vp + voff[dt]);

    // PV: in-register P remap via shfl, then O[qr][d] += P[qr][s]·V[s][d]
#pragma unroll
    for (int mtq = 0; mtq < 4; ++mtq) {
      const int a0 = __shfl(wd[mtq][0], sl0), b0 = __shfl(wd[mtq][2], sl0);
      const int a1 = __shfl(wd[mtq][1], sl0), b1 = __shfl(wd[mtq][3], sl0);
      const int a2 = __shfl(wd[mtq][0], sl1), b2 = __shfl(wd[mtq][2], sl1);
      const int a3 = __shfl(wd[mtq][1], sl1), b3 = __shfl(wd[mtq][3], sl1);
      i32x4 pw;
      pw[0] = hi2 ? b0 : a0;
      pw[1] = hi2 ? b1 : a1;
      pw[2] = hi2 ? b2 : a2;
      pw[3] = hi2 ? b3 : a3;
      const bf16x8 pa = __builtin_bit_cast(bf16x8, pw);
#pragma unroll
      for (int dt = 0; dt < 4; ++dt)
        oacc[mtq][dt] = __builtin_amdgcn_mfma_f32_16x16x32_bf16(pa, vbf[dt], oacc[mtq][dt], 0, 0, 0);
    }
  }

  __syncthreads();  // all waves done with loop (and long done with qs)

  // Z: reduce over quads in-wave, stash per-wave rows
#pragma unroll
  for (int nt = 0; nt < 4; ++nt) {
    float z = zrun[nt];
    z += __shfl_xor(z, 16);
    z += __shfl_xor(z, 32);
    if (quad == 0) sm.zred[w][nt * 16 + l15] = z;
  }
  for (int i = tid; i < 64 * 64; i += 256) sm.u.obuf[i] = 0.f;
  __syncthreads();
#pragma unroll
  for (int mtq = 0; mtq < 4; ++mtq)
#pragma unroll
    for (int r = 0; r < 4; ++r) {
      const int qr = mtq * 16 + quad * 4 + r;
#pragma unroll
      for (int dt = 0; dt < 4; ++dt)
        atomicAdd(&sm.u.obuf[qr * 64 + dt * 16 + l15], oacc[mtq][dt][r]);
    }
  __syncthreads();
  {  // scatter partial O (unnormalized) and partial Z to global accumulators
    const int qr = tid >> 2, seg = tid & 3;
    const int l = l0 + qr;
    if (l < U_SEL) {
      const int row = tkb[l];
      float* op = &out[((size_t)bh * T_DIM + row) * 64 + seg * 16];
      const float* ob = &sm.u.obuf[qr * 64 + seg * 16];
#pragma unroll
      for (int j = 0; j < 16; ++j) atomicAdd(&op[j], ob[j]);
    }
    if (tid < 64) {
      const float Zt = sm.zred[0][tid] + sm.zred[1][tid] + sm.zred[2][tid] + sm.zred[3][tid];
      if (l0 + tid < U_SEL) atomicAdd(&zacc[bh * 640 + l0 + tid], Zt);
    }
  }
}

// ====== Phase D: normalize selected rows by 1/Z ======
__global__ __launch_bounds__(256) void normalize_kernel(
    const int* __restrict__ topk, const float* __restrict__ zacc,
    float* __restrict__ out) {
  const int b = blockIdx.x;  // 320
  const int bh = b & 31;
  const int l0 = (b >> 5) * 64;
  const int tid = threadIdx.x;
  const int qr = tid >> 2, seg = tid & 3;
  const int l = l0 + qr;
  if (l >= U_SEL) return;
  const int row = topk[bh * U_SEL + l];
  const float inv = 1.0f / zacc[bh * 640 + l];
  float* op = &out[((size_t)bh * T_DIM + row) * 64 + seg * 16];
#pragma unroll
  for (int j = 0; j < 4; ++j) {
    float4 o = *(float4*)&op[j * 4];
    o.x *= inv; o.y *= inv; o.z *= inv; o.w *= inv;
    *(float4*)&op[j * 4] = o;
  }
}

extern "C" void kernel_launch(void* const* d_in, const int* in_sizes, int n_in,
                              void* d_out, int out_size, void* d_ws, size_t ws_size,
                              hipStream_t stream) {
  const float* q = (const float*)d_in[0];
  const float* k = (const float*)d_in[1];
  const float* v = (const float*)d_in[2];
  float* out = (float*)d_out;
  // workspace: zw 1 MB | topk 78 KB | zacc 96 KB | kimg 16 MB | vt 8 MB  (~25.3 MB)
  char* ws = (char*)d_ws;
  float2* zw = (float2*)ws;                                  // [2][32][2048] float2
  int* topk = (int*)(ws + 1048576);
  float* zacc = (float*)(ws + 1131520);                      // [32][640] f32 (+ zero pad)
  unsigned short* kimg = (unsigned short*)(ws + 1310720);    // 32 bh x 32 tiles x 16 KB
  unsigned short* vt_g = (unsigned short*)(ws + 18087936);   // 32 bh x 16 tiles x 16 KB

  convert_kernel<<<dim3(2051), dim3(256), 0, stream>>>(k, v, kimg, vt_g, out, zacc);
  kl_score_mfma<<<dim3(1024), dim3(256), 0, stream>>>(q, kimg, zw);
  topk_kernel<<<dim3(BH_DIM), dim3(1024), 0, stream>>>(zw, topk);
  sparse_attn_mfma<<<dim3(1280), dim3(256), 0, stream>>>(q, kimg, vt_g, topk, out, zacc);
  normalize_kernel<<<dim3(320), dim3(256), 0, stream>>>(topk, zacc, out);
}

// Round 3
// 324.734 us; speedup vs baseline: 1.7549x; 1.7549x over previous
//
#include <hip/hip_runtime.h>
#include <math.h>

#define T_DIM 2048
#define S_DIM 2048
#define D_DIM 64
#define BH_DIM 32
#define U_SEL 614
#define LOG_S_D 7.624618986159398
#define LOG2E_F 1.4426950408889634f
#define LN2_D 0.6931471805599453
#define SCL_Q (0.125f * LOG2E_F)  // q scale folded with log2e: scores in log2 domain

typedef __attribute__((ext_vector_type(8))) short bf16x8;
typedef __attribute__((ext_vector_type(4))) short bf16x4;
typedef __attribute__((ext_vector_type(4))) float f32x4;
typedef __attribute__((ext_vector_type(4))) int i32x4;

__device__ __forceinline__ unsigned short bf16_rne(float x) {
  unsigned u = __float_as_uint(x);
  u += 0x7FFF + ((u >> 16) & 1);
  return (unsigned short)(u >> 16);
}
__device__ __forceinline__ float bf16_to_f(unsigned short h) {
  return __uint_as_float(((unsigned)h) << 16);
}
__device__ __forceinline__ int cvt_pk_bf16(float lo, float hi) {
  int r;
  asm("v_cvt_pk_bf16_f32 %0, %1, %2" : "=v"(r) : "v"(lo), "v"(hi));
  return r;
}

#define GLD_LDS16(g, l)                                                        \
  __builtin_amdgcn_global_load_lds(                                            \
      (const __attribute__((address_space(1))) unsigned int*)(const void*)(g), \
      (__attribute__((address_space(3))) unsigned int*)(void*)(l), 16, 0, 0)

// stage 16 KB image: 4 waves x 4 instr x 64 lanes x 16 B
__device__ __forceinline__ void stage_img16(const unsigned short* __restrict__ g,
                                            unsigned short* l, int lane, int w) {
#pragma unroll
  for (int it = 0; it < 4; ++it) {
    const int chunk = it * 4 + w;
    GLD_LDS16((const char*)g + chunk * 1024 + lane * 16, (char*)l + chunk * 1024);
  }
}

// swizzled image, 64-wide rows: element (r,d) at r*64 + ((d>>3)^(r&7))*8 + (d&7)
__device__ __forceinline__ bf16x8 ldfrag_sw(const unsigned short* buf, int row, int chunk) {
  return *(const bf16x8*)(buf + (row << 6) + (((chunk) ^ (row & 7)) << 3));
}
// two stacked 64-row images (rows 0..127)
__device__ __forceinline__ bf16x8 ldfrag_k128(const unsigned short* buf, int row, int chunk) {
  return *(const bf16x8*)(buf + ((row >> 6) << 12) + ((row & 63) << 6) +
                          (((chunk) ^ (row & 7)) << 3));
}

// ====== convert: K -> 64-row tiles [hi 8KB | lo 8KB] swizzled; V -> V^T images; zero(out) ======
__global__ __launch_bounds__(256) void convert_kernel(
    const float* __restrict__ kin, const float* __restrict__ vin,
    unsigned short* __restrict__ kimg, unsigned short* __restrict__ vt_g,
    float* __restrict__ out) {
  __shared__ float vld[128][65];
  const int jb = blockIdx.x;
  const int tid = threadIdx.x;
  if (jb < 1024) {  // K: 32 bh x 32 tiles of 64 rows
    const int bh = jb >> 5, tl = jb & 31;
    const float* src = kin + ((size_t)bh * 2048 + tl * 64) * 64;
    unsigned short* dst = kimg + (size_t)(bh * 32 + tl) * 8192;
#pragma unroll
    for (int g = 0; g < 2; ++g) {
      const int flat = g * 256 + tid;  // 512 chunks = 64 rows x 8
      const int r = flat >> 3, c = flat & 7;
      const float4 f0 = *(const float4*)(src + r * 64 + c * 8);
      const float4 f1 = *(const float4*)(src + r * 64 + c * 8 + 4);
      const float xs[8] = {f0.x, f0.y, f0.z, f0.w, f1.x, f1.y, f1.z, f1.w};
      bf16x8 hv, lv;
#pragma unroll
      for (int j = 0; j < 8; ++j) {
        const unsigned short h = bf16_rne(xs[j]);
        hv[j] = (short)h;
        lv[j] = (short)bf16_rne(xs[j] - bf16_to_f(h));
      }
      const int base = (r << 6) + ((c ^ (r & 7)) << 3);
      *(bf16x8*)(dst + base) = hv;
      *(bf16x8*)(dst + 4096 + base) = lv;
    }
  } else if (jb < 1536) {  // V^T: [64 d][128 s] bf16, chunk ^ (d&15)
    const int jv = jb - 1024;
    const int bh = jv >> 4, tl = jv & 15;
    const float* src = vin + ((size_t)bh * 2048 + tl * 128) * 64;
#pragma unroll
    for (int g = 0; g < 8; ++g) {
      const int f = g * 256 + tid;
      const int r = f >> 4, c4 = f & 15;
      const float4 x = *(const float4*)(src + r * 64 + c4 * 4);
      vld[r][c4 * 4 + 0] = x.x;
      vld[r][c4 * 4 + 1] = x.y;
      vld[r][c4 * 4 + 2] = x.z;
      vld[r][c4 * 4 + 3] = x.w;
    }
    __syncthreads();
    unsigned short* dst = vt_g + (size_t)(bh * 16 + tl) * 8192;
#pragma unroll
    for (int g = 0; g < 4; ++g) {
      const int oc = g * 256 + tid;
      const int d = oc >> 4, cc = oc & 15;
      bf16x8 hv;
#pragma unroll
      for (int j = 0; j < 8; ++j) hv[j] = (short)bf16_rne(vld[cc * 8 + j][d]);
      *(bf16x8*)(dst + (d << 7) + (((cc ^ (d & 15))) << 3)) = hv;
    }
  } else {  // zero d_out: 512 blocks x 2048 float4
    float4* o4 = (float4*)out;
    const size_t b = (size_t)(jb - 1536);
#pragma unroll
    for (int g = 0; g < 8; ++g)
      o4[b * 2048 + g * 256 + tid] = make_float4(0.f, 0.f, 0.f, 0.f);
  }
}

// ====== Phase A: partial (Z,W) per (t-row, s-half), bf16x3 MFMA, BK=64 dbuf ======
// grid 1024: bh = b&31 (XCD-local), ttile = (b>>5)&15, shalf = b>>9
__global__ __launch_bounds__(256, 4) void kl_score_mfma(
    const float* __restrict__ q, const unsigned short* __restrict__ kimg,
    float2* __restrict__ zw) {
  __shared__ __align__(16) unsigned short lbuf[2][8192];  // 2 x 16 KB
  const int b = blockIdx.x;
  const int bh = b & 31;
  const int t0 = ((b >> 5) & 15) * 128;
  const int shalf = b >> 9;
  const int tid = threadIdx.x;
  const int lane = tid & 63, w = tid >> 6, quad = lane >> 4, l15 = lane & 15;
  const float* qb = q + (size_t)bh * (2048 * 64) + (size_t)t0 * 64;
  const unsigned short* kb = kimg + (size_t)bh * (32 * 8192);
  const int tg0 = shalf * 16;

  {  // q tile -> hi image in lbuf[0], lo image in lbuf[1] (scaled by 0.125*log2e)
#pragma unroll
    for (int g = 0; g < 4; ++g) {
      const int flat = g * 256 + tid;  // 1024 chunks = 128 rows x 8
      const int r = flat >> 3, c = flat & 7;
      const float4 f0 = *(const float4*)(qb + r * 64 + c * 8);
      const float4 f1 = *(const float4*)(qb + r * 64 + c * 8 + 4);
      const float xs[8] = {f0.x, f0.y, f0.z, f0.w, f1.x, f1.y, f1.z, f1.w};
      bf16x8 hv, lv;
#pragma unroll
      for (int j = 0; j < 8; ++j) {
        const float x = xs[j] * SCL_Q;
        const unsigned short h = bf16_rne(x);
        hv[j] = (short)h;
        lv[j] = (short)bf16_rne(x - bf16_to_f(h));
      }
      const int r2 = r & 63, hi2 = r >> 6;  // rows 0-63 -> lbuf[x][0..4096), 64-127 -> +4096
      const int base = hi2 * 4096 + (r2 << 6) + ((c ^ (r2 & 7)) << 3);
      *(bf16x8*)(&lbuf[0][0] + base) = hv;
      *(bf16x8*)(&lbuf[1][0] + base) = lv;
    }
  }
  __syncthreads();

  bf16x8 ah[2][2], al[2][2];  // persistent q A-fragments (wave w: t-rows w*32..w*32+31)
#pragma unroll
  for (int rt = 0; rt < 2; ++rt) {
    const int row = w * 32 + rt * 16 + l15;
#pragma unroll
    for (int kc = 0; kc < 2; ++kc) {
      ah[rt][kc] = ldfrag_k128(&lbuf[0][0], row, kc * 4 + quad);
      al[rt][kc] = ldfrag_k128(&lbuf[1][0], row, kc * 4 + quad);
    }
  }
  __syncthreads();

  stage_img16(kb + (size_t)tg0 * 8192, &lbuf[0][0], lane, w);
  __syncthreads();  // drain tile 0

  float Zf[8], Wf[8];
#pragma unroll
  for (int i = 0; i < 8; ++i) { Zf[i] = 0.f; Wf[i] = 0.f; }

  for (int t = 0; t < 16; ++t) {
    if (t < 15)
      stage_img16(kb + (size_t)(tg0 + t + 1) * 8192, &lbuf[(t + 1) & 1][0], lane, w);
    const unsigned short* cb = &lbuf[t & 1][0];  // [hi 4096 | lo 4096] elems, 64 rows

    f32x4 acc[2][4];
#pragma unroll
    for (int rt = 0; rt < 2; ++rt)
#pragma unroll
      for (int ct = 0; ct < 4; ++ct) acc[rt][ct] = (f32x4){0.f, 0.f, 0.f, 0.f};

#pragma unroll
    for (int ct = 0; ct < 4; ++ct) {
      const int srow = ct * 16 + l15;
      const bf16x8 bh0 = ldfrag_sw(cb, srow, quad);
      const bf16x8 bl0 = ldfrag_sw(cb + 4096, srow, quad);
      const bf16x8 bh1 = ldfrag_sw(cb, srow, 4 + quad);
      const bf16x8 bl1 = ldfrag_sw(cb + 4096, srow, 4 + quad);
#pragma unroll
      for (int rt = 0; rt < 2; ++rt) {
        f32x4 c = acc[rt][ct];
        c = __builtin_amdgcn_mfma_f32_16x16x32_bf16(ah[rt][0], bh0, c, 0, 0, 0);
        c = __builtin_amdgcn_mfma_f32_16x16x32_bf16(al[rt][0], bh0, c, 0, 0, 0);
        c = __builtin_amdgcn_mfma_f32_16x16x32_bf16(ah[rt][0], bl0, c, 0, 0, 0);
        c = __builtin_amdgcn_mfma_f32_16x16x32_bf16(ah[rt][1], bh1, c, 0, 0, 0);
        c = __builtin_amdgcn_mfma_f32_16x16x32_bf16(al[rt][1], bh1, c, 0, 0, 0);
        c = __builtin_amdgcn_mfma_f32_16x16x32_bf16(ah[rt][1], bl1, c, 0, 0, 0);
        acc[rt][ct] = c;
      }
    }

    // no-max epilogue (log2 domain): e = 2^t, W2 += e*t  (fp32 accumulators)
#pragma unroll
    for (int rt = 0; rt < 2; ++rt)
#pragma unroll
      for (int r = 0; r < 4; ++r) {
        float zp = 0.f, wp = 0.f;
#pragma unroll
        for (int ct = 0; ct < 4; ++ct) {
          const float tt = acc[rt][ct][r];
          const float e = exp2f(tt);
          zp += e;
          wp = fmaf(e, tt, wp);
        }
        Zf[rt * 4 + r] += zp;
        Wf[rt * 4 + r] += wp;
      }
    __syncthreads();  // readers done; drains prefetch of t+1
  }

#pragma unroll
  for (int i = 0; i < 8; ++i) {
    float Zt = Zf[i], Wt = Wf[i];
#pragma unroll
    for (int mask = 1; mask <= 8; mask <<= 1) {
      Zt += __shfl_xor(Zt, mask);
      Wt += __shfl_xor(Wt, mask);
    }
    if (l15 == 0) {
      const int row = t0 + w * 32 + (i >> 2) * 16 + quad * 4 + (i & 3);
      zw[((size_t)shalf * 32 + bh) * 2048 + row] = make_float2(Zt, Wt);
    }
  }
}

// ====== Phase B: kl from (Z,W) halves + exact top-614, bitonic, 1024 threads ======
__global__ __launch_bounds__(1024) void topk_kernel(const float2* __restrict__ zw,
                                                    int* __restrict__ topk) {
  __shared__ float sv[2048];
  __shared__ int si[2048];
  const int bh = blockIdx.x;
  const int tid = threadIdx.x;
  for (int i = tid; i < 2048; i += 1024) {
    const float2 a = zw[(size_t)bh * 2048 + i];
    const float2 c = zw[(size_t)(32 + bh) * 2048 + i];
    const double Z = (double)a.x + (double)c.x;
    const double W = (double)a.y + (double)c.y;
    sv[i] = (float)(LN2_D * (W / Z) - log(Z) + LOG_S_D);
    si[i] = i;
  }
  __syncthreads();
  for (int kk = 2; kk <= 2048; kk <<= 1) {
    for (int j = kk >> 1; j > 0; j >>= 1) {
      const int p = tid;
      const int i = ((p & ~(j - 1)) << 1) | (p & (j - 1));
      const int pr = i | j;
      const float v1 = sv[i], v2 = sv[pr];
      const int i1 = si[i], i2 = si[pr];
      const bool beforePI = (v2 > v1) || (v2 == v1 && i2 < i1);
      const bool dirDesc = ((i & kk) == 0);
      const bool doSwap = dirDesc ? beforePI : !beforePI;
      if (doSwap) { sv[i] = v2; sv[pr] = v1; si[i] = i2; si[pr] = i1; }
      __syncthreads();
    }
  }
  for (int i = tid; i < U_SEL; i += 1024) topk[bh * U_SEL + i] = si[i];
}

// ====== Phase C: bf16 MFMA attention, all-register K/V/P path, s-split 4-way ======
// Wave w exclusively owns s-rows [w*32, w*32+32) of each 128-s tile -> K and V
// fragments load straight from the pre-swizzled global images to registers
// (no LDS staging, no mid-loop barriers). P remap is intra-wave (cvt_pk+shfl).
// Cross-block merge: plain f32 partial stores per (bh,schunk); NO global atomics
// (round-2 lesson: 5M scalar atomics -> 216MB serialized RMW traffic, 5x slower).
struct __align__(16) SmC {
  union { unsigned short qs[64 * 64]; float obuf[64 * 64]; } u;  // 16 KB (qs dead after qf load)
  float zred[4][64];                                             // 1 KB
};

// grid 1280: bh = b&31 (XCD-local), t = b>>5: schunk = t&3 (512 s), l0 = (t>>2)*64
__global__ __launch_bounds__(256, 3) void sparse_attn_mfma(
    const float* __restrict__ q, const unsigned short* __restrict__ kimg,
    const unsigned short* __restrict__ vt_g, const int* __restrict__ topk,
    float* __restrict__ opart, float* __restrict__ zpart) {
  __shared__ SmC sm;
  const int b = blockIdx.x;
  const int bh = b & 31;
  const int t = b >> 5;
  const int schunk = t & 3;
  const int l0 = (t >> 2) * 64;
  const int tid = threadIdx.x;
  const int lane = tid & 63, w = tid >> 6, quad = lane >> 4, l15 = lane & 15;
  const float* qb = q + (size_t)bh * (2048 * 64);
  const char* kbB = (const char*)(kimg + (size_t)bh * (32 * 8192));
  const char* vtB = (const char*)(vt_g + (size_t)bh * (16 * 8192));
  const int* tkb = topk + bh * U_SEL;

  {  // gather selected q rows -> bf16 * (0.125*log2e), swizzled image in LDS
#pragma unroll
    for (int g = 0; g < 2; ++g) {
      const int ch = g * 256 + tid;
      const int r = ch >> 3, c = ch & 7;
      const int l = l0 + r;
      const int row = (l < U_SEL) ? tkb[l] : tkb[0];
      const float4 f0 = *(const float4*)(qb + (size_t)row * 64 + c * 8);
      const float4 f1 = *(const float4*)(qb + (size_t)row * 64 + c * 8 + 4);
      const float xs[8] = {f0.x, f0.y, f0.z, f0.w, f1.x, f1.y, f1.z, f1.w};
      bf16x8 hv;
#pragma unroll
      for (int j = 0; j < 8; ++j) hv[j] = (short)bf16_rne(xs[j] * SCL_Q);
      *(bf16x8*)&sm.u.qs[(r << 6) + ((c ^ (r & 7)) << 3)] = hv;
    }
  }
  __syncthreads();

  bf16x8 qf[4][2];  // persistent q B-fragments
#pragma unroll
  for (int nt = 0; nt < 4; ++nt)
#pragma unroll
    for (int kc = 0; kc < 2; ++kc)
      qf[nt][kc] = ldfrag_sw(sm.u.qs, nt * 16 + l15, kc * 4 + quad);

  // per-lane static byte offsets into the swizzled K / V^T global images
  int kq[2][2];
#pragma unroll
  for (int mt = 0; mt < 2; ++mt) {
    const int base = w * 32 + mt * 16;  // row in 128-row K pair
    const int img = base >> 6;          // which 64-row image (0/1)
    const int row64 = (base & 63) + l15;
    kq[mt][0] = img * 16384 + row64 * 128 + ((quad ^ (l15 & 7)) << 4);
    kq[mt][1] = img * 16384 + row64 * 128 + (((4 + quad) ^ (l15 & 7)) << 4);
  }
  int voff[4];
#pragma unroll
  for (int dt = 0; dt < 4; ++dt)
    voff[dt] = (dt * 16 + l15) * 256 + (((w * 4 + quad) ^ l15) << 4);

  const int sl0 = ((quad & 1) << 5) + l15;  // shfl source lanes for P remap
  const int sl1 = sl0 + 16;
  const bool hi2 = quad >= 2;

  float zrun[4] = {0.f, 0.f, 0.f, 0.f};
  f32x4 oacc[4][4];
#pragma unroll
  for (int a = 0; a < 4; ++a)
#pragma unroll
    for (int b2 = 0; b2 < 4; ++b2) oacc[a][b2] = (f32x4){0.f, 0.f, 0.f, 0.f};

  for (int st = 0; st < 4; ++st) {
    const char* kp = kbB + (size_t)(schunk * 4 + st) * 32768;  // 2 K-images / tile
    const char* vp = vtB + (size_t)(schunk * 4 + st) * 16384;  // 1 V^T image / tile

    // K fragments: straight to registers
    const bf16x8 a00 = *(const bf16x8*)(kp + kq[0][0]);
    const bf16x8 a01 = *(const bf16x8*)(kp + kq[0][1]);
    const bf16x8 a10 = *(const bf16x8*)(kp + kq[1][0]);
    const bf16x8 a11 = *(const bf16x8*)(kp + kq[1][1]);

    // S^T = K·q^T : C[m=s][n=qr]; lane holds qr=l15, s-local = mt*16+quad*4+r
    f32x4 sacc[2][4];
#pragma unroll
    for (int mt = 0; mt < 2; ++mt)
#pragma unroll
      for (int nt = 0; nt < 4; ++nt) {
        f32x4 c = (f32x4){0.f, 0.f, 0.f, 0.f};
        c = __builtin_amdgcn_mfma_f32_16x16x32_bf16(mt ? a10 : a00, qf[nt][0], c, 0, 0, 0);
        c = __builtin_amdgcn_mfma_f32_16x16x32_bf16(mt ? a11 : a01, qf[nt][1], c, 0, 0, 0);
        sacc[mt][nt] = c;
      }

    // p = 2^t; pack to bf16 pairs (word k holds s-pair {base+2k, base+2k+1})
    int wd[4][4];
#pragma unroll
    for (int nt = 0; nt < 4; ++nt) {
      const float p0 = exp2f(sacc[0][nt][0]), p1 = exp2f(sacc[0][nt][1]);
      const float p2 = exp2f(sacc[0][nt][2]), p3 = exp2f(sacc[0][nt][3]);
      const float p4 = exp2f(sacc[1][nt][0]), p5 = exp2f(sacc[1][nt][1]);
      const float p6 = exp2f(sacc[1][nt][2]), p7 = exp2f(sacc[1][nt][3]);
      zrun[nt] += (p0 + p1 + p2 + p3) + (p4 + p5 + p6 + p7);
      wd[nt][0] = cvt_pk_bf16(p0, p1);
      wd[nt][1] = cvt_pk_bf16(p2, p3);
      wd[nt][2] = cvt_pk_bf16(p4, p5);
      wd[nt][3] = cvt_pk_bf16(p6, p7);
    }

    // V fragments: straight to registers (latency covered by shfl phase + TLP)
    bf16x8 vbf[4];
#pragma unroll
    for (int dt = 0; dt < 4; ++dt) vbf[dt] = *(const bf16x8*)(vp + voff[dt]);

    // PV: in-register P remap via shfl, then O[qr][d] += P[qr][s]·V[s][d]
#pragma unroll
    for (int mtq = 0; mtq < 4; ++mtq) {
      const int a0 = __shfl(wd[mtq][0], sl0), b0 = __shfl(wd[mtq][2], sl0);
      const int a1 = __shfl(wd[mtq][1], sl0), b1 = __shfl(wd[mtq][3], sl0);
      const int a2 = __shfl(wd[mtq][0], sl1), b2 = __shfl(wd[mtq][2], sl1);
      const int a3 = __shfl(wd[mtq][1], sl1), b3 = __shfl(wd[mtq][3], sl1);
      i32x4 pw;
      pw[0] = hi2 ? b0 : a0;
      pw[1] = hi2 ? b1 : a1;
      pw[2] = hi2 ? b2 : a2;
      pw[3] = hi2 ? b3 : a3;
      const bf16x8 pa = __builtin_bit_cast(bf16x8, pw);
#pragma unroll
      for (int dt = 0; dt < 4; ++dt)
        oacc[mtq][dt] = __builtin_amdgcn_mfma_f32_16x16x32_bf16(pa, vbf[dt], oacc[mtq][dt], 0, 0, 0);
    }
  }

  __syncthreads();  // all waves done with loop (and long done with qs)

  // Z: reduce over quads in-wave, stash per-wave rows
#pragma unroll
  for (int nt = 0; nt < 4; ++nt) {
    float z = zrun[nt];
    z += __shfl_xor(z, 16);
    z += __shfl_xor(z, 32);
    if (quad == 0) sm.zred[w][nt * 16 + l15] = z;
  }
  for (int i = tid; i < 64 * 64; i += 256) sm.u.obuf[i] = 0.f;
  __syncthreads();
#pragma unroll
  for (int mtq = 0; mtq < 4; ++mtq)
#pragma unroll
    for (int r = 0; r < 4; ++r) {
      const int qr = mtq * 16 + quad * 4 + r;
#pragma unroll
      for (int dt = 0; dt < 4; ++dt)
        atomicAdd(&sm.u.obuf[qr * 64 + dt * 16 + l15], oacc[mtq][dt][r]);
    }
  __syncthreads();
  {  // plain coalesced partial stores (no global atomics)
    const int qr = tid >> 2, seg = tid & 3;
    float* op = &opart[(((size_t)(bh * 4 + schunk) * 640) + l0 + qr) * 64 + seg * 16];
    const float* ob = &sm.u.obuf[qr * 64 + seg * 16];
#pragma unroll
    for (int j = 0; j < 4; ++j) *(float4*)&op[j * 4] = *(const float4*)&ob[j * 4];
    if (tid < 64) {
      const float Zt = sm.zred[0][tid] + sm.zred[1][tid] + sm.zred[2][tid] + sm.zred[3][tid];
      zpart[(bh * 4 + schunk) * 640 + l0 + tid] = Zt;
    }
  }
}

// ====== Phase D: merge 4 schunk partials, normalize, scatter to out ======
__global__ __launch_bounds__(256) void normalize_kernel(
    const int* __restrict__ topk, const float* __restrict__ zpart,
    const float* __restrict__ opart, float* __restrict__ out) {
  const int b = blockIdx.x;  // 320
  const int bh = b & 31;
  const int l0 = (b >> 5) * 64;
  const int tid = threadIdx.x;
  const int qr = tid >> 2, seg = tid & 3;
  const int l = l0 + qr;
  if (l >= U_SEL) return;
  const int row = topk[bh * U_SEL + l];
  float Z = 0.f;
#pragma unroll
  for (int sc = 0; sc < 4; ++sc) Z += zpart[(bh * 4 + sc) * 640 + l];
  const float inv = 1.0f / Z;
  float* op = &out[((size_t)bh * T_DIM + row) * 64 + seg * 16];
#pragma unroll
  for (int j = 0; j < 4; ++j) {
    float4 o = make_float4(0.f, 0.f, 0.f, 0.f);
#pragma unroll
    for (int sc = 0; sc < 4; ++sc) {
      const float4 p = *(const float4*)&opart[(((size_t)(bh * 4 + sc) * 640) + l) * 64 + seg * 16 + j * 4];
      o.x += p.x; o.y += p.y; o.z += p.z; o.w += p.w;
    }
    o.x *= inv; o.y *= inv; o.z *= inv; o.w *= inv;
    *(float4*)&op[j * 4] = o;
  }
}

extern "C" void kernel_launch(void* const* d_in, const int* in_sizes, int n_in,
                              void* d_out, int out_size, void* d_ws, size_t ws_size,
                              hipStream_t stream) {
  const float* q = (const float*)d_in[0];
  const float* k = (const float*)d_in[1];
  const float* v = (const float*)d_in[2];
  float* out = (float*)d_out;
  // workspace: zw 1MB | topk 80KB | zpart 320KB | kimg 16MB | vt 8MB | opart 21MB (~45.5MB)
  char* ws = (char*)d_ws;
  float2* zw = (float2*)ws;                                  // [2][32][2048] float2
  int* topk = (int*)(ws + 1048576);
  float* zpart = (float*)(ws + 1131520);                     // [32][4][640] f32
  unsigned short* kimg = (unsigned short*)(ws + 1572864);    // 32 bh x 32 tiles x 16 KB
  unsigned short* vt_g = (unsigned short*)(ws + 18350080);   // 32 bh x 16 tiles x 16 KB
  float* opart = (float*)(ws + 26738688);                    // [32][4][640][64] f32

  convert_kernel<<<dim3(2048), dim3(256), 0, stream>>>(k, v, kimg, vt_g, out);
  kl_score_mfma<<<dim3(1024), dim3(256), 0, stream>>>(q, kimg, zw);
  topk_kernel<<<dim3(BH_DIM), dim3(1024), 0, stream>>>(zw, topk);
  sparse_attn_mfma<<<dim3(1280), dim3(256), 0, stream>>>(q, kimg, vt_g, topk, opart, zpart);
  normalize_kernel<<<dim3(320), dim3(256), 0, stream>>>(topk, zpart, opart, out);
}

// Round 4
// 268.546 us; speedup vs baseline: 2.1221x; 1.2092x over previous
//
#include <hip/hip_runtime.h>
#include <math.h>

#define T_DIM 2048
#define S_DIM 2048
#define D_DIM 64
#define BH_DIM 32
#define U_SEL 614
#define LOG_S_D 7.624618986159398
#define LOG2E_F 1.4426950408889634f
#define LN2_D 0.6931471805599453
#define SCL_Q (0.125f * LOG2E_F)  // q scale folded with log2e: scores in log2 domain

typedef __attribute__((ext_vector_type(8))) short bf16x8;
typedef __attribute__((ext_vector_type(4))) short bf16x4;
typedef __attribute__((ext_vector_type(4))) float f32x4;
typedef __attribute__((ext_vector_type(4))) int i32x4;

__device__ __forceinline__ unsigned short bf16_rne(float x) {
  unsigned u = __float_as_uint(x);
  u += 0x7FFF + ((u >> 16) & 1);
  return (unsigned short)(u >> 16);
}
__device__ __forceinline__ float bf16_to_f(unsigned short h) {
  return __uint_as_float(((unsigned)h) << 16);
}
__device__ __forceinline__ int cvt_pk_bf16(float lo, float hi) {
  int r;
  asm("v_cvt_pk_bf16_f32 %0, %1, %2" : "=v"(r) : "v"(lo), "v"(hi));
  return r;
}

#define GLD_LDS16(g, l)                                                        \
  __builtin_amdgcn_global_load_lds(                                            \
      (const __attribute__((address_space(1))) unsigned int*)(const void*)(g), \
      (__attribute__((address_space(3))) unsigned int*)(void*)(l), 16, 0, 0)

// stage 16 KB image: 4 waves x 4 instr x 64 lanes x 16 B
__device__ __forceinline__ void stage_img16(const unsigned short* __restrict__ g,
                                            unsigned short* l, int lane, int w) {
#pragma unroll
  for (int it = 0; it < 4; ++it) {
    const int chunk = it * 4 + w;
    GLD_LDS16((const char*)g + chunk * 1024 + lane * 16, (char*)l + chunk * 1024);
  }
}
// stage 8 KB image: 4 waves x 2 instr
__device__ __forceinline__ void stage_img8(const unsigned short* __restrict__ g,
                                           unsigned short* l, int lane, int w) {
#pragma unroll
  for (int it = 0; it < 2; ++it) {
    const int chunk = it * 4 + w;
    GLD_LDS16((const char*)g + chunk * 1024 + lane * 16, (char*)l + chunk * 1024);
  }
}

// swizzled image, 64-wide rows: element (r,d) at r*64 + ((d>>3)^(r&7))*8 + (d&7)
__device__ __forceinline__ bf16x8 ldfrag_sw(const unsigned short* buf, int row, int chunk) {
  return *(const bf16x8*)(buf + (row << 6) + (((chunk) ^ (row & 7)) << 3));
}
// two stacked 64-row images (rows 0..127)
__device__ __forceinline__ bf16x8 ldfrag_k128(const unsigned short* buf, int row, int chunk) {
  return *(const bf16x8*)(buf + ((row >> 6) << 12) + ((row & 63) << 6) +
                          (((chunk) ^ (row & 7)) << 3));
}

// ====== convert: K -> 64-row tiles [hi 8KB | lo 8KB] swizzled; V -> V^T images; zero(out) ======
__global__ __launch_bounds__(256) void convert_kernel(
    const float* __restrict__ kin, const float* __restrict__ vin,
    unsigned short* __restrict__ kimg, unsigned short* __restrict__ vt_g,
    float* __restrict__ out) {
  __shared__ float vld[128][65];
  const int jb = blockIdx.x;
  const int tid = threadIdx.x;
  if (jb < 1024) {  // K: 32 bh x 32 tiles of 64 rows
    const int bh = jb >> 5, tl = jb & 31;
    const float* src = kin + ((size_t)bh * 2048 + tl * 64) * 64;
    unsigned short* dst = kimg + (size_t)(bh * 32 + tl) * 8192;
#pragma unroll
    for (int g = 0; g < 2; ++g) {
      const int flat = g * 256 + tid;  // 512 chunks = 64 rows x 8
      const int r = flat >> 3, c = flat & 7;
      const float4 f0 = *(const float4*)(src + r * 64 + c * 8);
      const float4 f1 = *(const float4*)(src + r * 64 + c * 8 + 4);
      const float xs[8] = {f0.x, f0.y, f0.z, f0.w, f1.x, f1.y, f1.z, f1.w};
      bf16x8 hv, lv;
#pragma unroll
      for (int j = 0; j < 8; ++j) {
        const unsigned short h = bf16_rne(xs[j]);
        hv[j] = (short)h;
        lv[j] = (short)bf16_rne(xs[j] - bf16_to_f(h));
      }
      const int base = (r << 6) + ((c ^ (r & 7)) << 3);
      *(bf16x8*)(dst + base) = hv;
      *(bf16x8*)(dst + 4096 + base) = lv;
    }
  } else if (jb < 1536) {  // V^T: [64 d][128 s] bf16, chunk ^ (d&15)
    const int jv = jb - 1024;
    const int bh = jv >> 4, tl = jv & 15;
    const float* src = vin + ((size_t)bh * 2048 + tl * 128) * 64;
#pragma unroll
    for (int g = 0; g < 8; ++g) {
      const int f = g * 256 + tid;
      const int r = f >> 4, c4 = f & 15;
      const float4 x = *(const float4*)(src + r * 64 + c4 * 4);
      vld[r][c4 * 4 + 0] = x.x;
      vld[r][c4 * 4 + 1] = x.y;
      vld[r][c4 * 4 + 2] = x.z;
      vld[r][c4 * 4 + 3] = x.w;
    }
    __syncthreads();
    unsigned short* dst = vt_g + (size_t)(bh * 16 + tl) * 8192;
#pragma unroll
    for (int g = 0; g < 4; ++g) {
      const int oc = g * 256 + tid;
      const int d = oc >> 4, cc = oc & 15;
      bf16x8 hv;
#pragma unroll
      for (int j = 0; j < 8; ++j) hv[j] = (short)bf16_rne(vld[cc * 8 + j][d]);
      *(bf16x8*)(dst + (d << 7) + (((cc ^ (d & 15))) << 3)) = hv;
    }
  } else {  // zero d_out: 512 blocks x 2048 float4
    float4* o4 = (float4*)out;
    const size_t b = (size_t)(jb - 1536);
#pragma unroll
    for (int g = 0; g < 8; ++g)
      o4[b * 2048 + g * 256 + tid] = make_float4(0.f, 0.f, 0.f, 0.f);
  }
}

// ====== Phase A: partial (Z,W) per (t-row, s-half), bf16x3 MFMA, BK=64 dbuf ======
// grid 1024: bh = b&31 (XCD-local), ttile = (b>>5)&15, shalf = b>>9
__global__ __launch_bounds__(256, 4) void kl_score_mfma(
    const float* __restrict__ q, const unsigned short* __restrict__ kimg,
    float2* __restrict__ zw) {
  __shared__ __align__(16) unsigned short lbuf[2][8192];  // 2 x 16 KB
  const int b = blockIdx.x;
  const int bh = b & 31;
  const int t0 = ((b >> 5) & 15) * 128;
  const int shalf = b >> 9;
  const int tid = threadIdx.x;
  const int lane = tid & 63, w = tid >> 6, quad = lane >> 4, l15 = lane & 15;
  const float* qb = q + (size_t)bh * (2048 * 64) + (size_t)t0 * 64;
  const unsigned short* kb = kimg + (size_t)bh * (32 * 8192);
  const int tg0 = shalf * 16;

  {  // q tile -> hi image in lbuf[0], lo image in lbuf[1] (scaled by 0.125*log2e)
#pragma unroll
    for (int g = 0; g < 4; ++g) {
      const int flat = g * 256 + tid;  // 1024 chunks = 128 rows x 8
      const int r = flat >> 3, c = flat & 7;
      const float4 f0 = *(const float4*)(qb + r * 64 + c * 8);
      const float4 f1 = *(const float4*)(qb + r * 64 + c * 8 + 4);
      const float xs[8] = {f0.x, f0.y, f0.z, f0.w, f1.x, f1.y, f1.z, f1.w};
      bf16x8 hv, lv;
#pragma unroll
      for (int j = 0; j < 8; ++j) {
        const float x = xs[j] * SCL_Q;
        const unsigned short h = bf16_rne(x);
        hv[j] = (short)h;
        lv[j] = (short)bf16_rne(x - bf16_to_f(h));
      }
      const int r2 = r & 63, hi2 = r >> 6;  // rows 0-63 -> lbuf[x][0..4096), 64-127 -> +4096
      const int base = hi2 * 4096 + (r2 << 6) + ((c ^ (r2 & 7)) << 3);
      *(bf16x8*)(&lbuf[0][0] + base) = hv;
      *(bf16x8*)(&lbuf[1][0] + base) = lv;
    }
  }
  __syncthreads();

  bf16x8 ah[2][2], al[2][2];  // persistent q A-fragments (wave w: t-rows w*32..w*32+31)
#pragma unroll
  for (int rt = 0; rt < 2; ++rt) {
    const int row = w * 32 + rt * 16 + l15;
#pragma unroll
    for (int kc = 0; kc < 2; ++kc) {
      ah[rt][kc] = ldfrag_k128(&lbuf[0][0], row, kc * 4 + quad);
      al[rt][kc] = ldfrag_k128(&lbuf[1][0], row, kc * 4 + quad);
    }
  }
  __syncthreads();

  stage_img16(kb + (size_t)tg0 * 8192, &lbuf[0][0], lane, w);
  __syncthreads();  // drain tile 0

  float Zf[8], Wf[8];
#pragma unroll
  for (int i = 0; i < 8; ++i) { Zf[i] = 0.f; Wf[i] = 0.f; }

  for (int t = 0; t < 16; ++t) {
    if (t < 15)
      stage_img16(kb + (size_t)(tg0 + t + 1) * 8192, &lbuf[(t + 1) & 1][0], lane, w);
    const unsigned short* cb = &lbuf[t & 1][0];  // [hi 4096 | lo 4096] elems, 64 rows

    f32x4 acc[2][4];
#pragma unroll
    for (int rt = 0; rt < 2; ++rt)
#pragma unroll
      for (int ct = 0; ct < 4; ++ct) acc[rt][ct] = (f32x4){0.f, 0.f, 0.f, 0.f};

#pragma unroll
    for (int ct = 0; ct < 4; ++ct) {
      const int srow = ct * 16 + l15;
      const bf16x8 bh0 = ldfrag_sw(cb, srow, quad);
      const bf16x8 bl0 = ldfrag_sw(cb + 4096, srow, quad);
      const bf16x8 bh1 = ldfrag_sw(cb, srow, 4 + quad);
      const bf16x8 bl1 = ldfrag_sw(cb + 4096, srow, 4 + quad);
#pragma unroll
      for (int rt = 0; rt < 2; ++rt) {
        f32x4 c = acc[rt][ct];
        c = __builtin_amdgcn_mfma_f32_16x16x32_bf16(ah[rt][0], bh0, c, 0, 0, 0);
        c = __builtin_amdgcn_mfma_f32_16x16x32_bf16(al[rt][0], bh0, c, 0, 0, 0);
        c = __builtin_amdgcn_mfma_f32_16x16x32_bf16(ah[rt][0], bl0, c, 0, 0, 0);
        c = __builtin_amdgcn_mfma_f32_16x16x32_bf16(ah[rt][1], bh1, c, 0, 0, 0);
        c = __builtin_amdgcn_mfma_f32_16x16x32_bf16(al[rt][1], bh1, c, 0, 0, 0);
        c = __builtin_amdgcn_mfma_f32_16x16x32_bf16(ah[rt][1], bl1, c, 0, 0, 0);
        acc[rt][ct] = c;
      }
    }

    // no-max epilogue (log2 domain): e = 2^t, W2 += e*t  (fp32 accumulators)
#pragma unroll
    for (int rt = 0; rt < 2; ++rt)
#pragma unroll
      for (int r = 0; r < 4; ++r) {
        float zp = 0.f, wp = 0.f;
#pragma unroll
        for (int ct = 0; ct < 4; ++ct) {
          const float tt = acc[rt][ct][r];
          const float e = exp2f(tt);
          zp += e;
          wp = fmaf(e, tt, wp);
        }
        Zf[rt * 4 + r] += zp;
        Wf[rt * 4 + r] += wp;
      }
    __syncthreads();  // readers done; drains prefetch of t+1
  }

#pragma unroll
  for (int i = 0; i < 8; ++i) {
    float Zt = Zf[i], Wt = Wf[i];
#pragma unroll
    for (int mask = 1; mask <= 8; mask <<= 1) {
      Zt += __shfl_xor(Zt, mask);
      Wt += __shfl_xor(Wt, mask);
    }
    if (l15 == 0) {
      const int row = t0 + w * 32 + (i >> 2) * 16 + quad * 4 + (i & 3);
      zw[((size_t)shalf * 32 + bh) * 2048 + row] = make_float2(Zt, Wt);
    }
  }
}

// ====== Phase B: kl from (Z,W) halves + exact top-614, bitonic, 1024 threads ======
__global__ __launch_bounds__(1024) void topk_kernel(const float2* __restrict__ zw,
                                                    int* __restrict__ topk) {
  __shared__ float sv[2048];
  __shared__ int si[2048];
  const int bh = blockIdx.x;
  const int tid = threadIdx.x;
  for (int i = tid; i < 2048; i += 1024) {
    const float2 a = zw[(size_t)bh * 2048 + i];
    const float2 c = zw[(size_t)(32 + bh) * 2048 + i];
    const double Z = (double)a.x + (double)c.x;
    const double W = (double)a.y + (double)c.y;
    sv[i] = (float)(LN2_D * (W / Z) - log(Z) + LOG_S_D);
    si[i] = i;
  }
  __syncthreads();
  for (int kk = 2; kk <= 2048; kk <<= 1) {
    for (int j = kk >> 1; j > 0; j >>= 1) {
      const int p = tid;
      const int i = ((p & ~(j - 1)) << 1) | (p & (j - 1));
      const int pr = i | j;
      const float v1 = sv[i], v2 = sv[pr];
      const int i1 = si[i], i2 = si[pr];
      const bool beforePI = (v2 > v1) || (v2 == v1 && i2 < i1);
      const bool dirDesc = ((i & kk) == 0);
      const bool doSwap = dirDesc ? beforePI : !beforePI;
      if (doSwap) { sv[i] = v2; sv[pr] = v1; si[i] = i2; si[pr] = i1; }
      __syncthreads();
    }
  }
  for (int i = tid; i < U_SEL; i += 1024) topk[bh * U_SEL + i] = si[i];
}

// ====== Phase C: LDS-staged K/V (contiguous gld_lds) + in-register P remap ======
// Hybrid of the two proven variants: round-0's fast contiguous staging path and
// round-3's in-register P (cvt_pk+shfl) which deletes the 20 KB ps buffer.
// LDS unions -> 40 KB -> 3 blocks/CU; s-split 2-way -> grid 640, ALL blocks
// co-resident (no dispatch tail), stage latency hidden by 3-block TLP.
// Merge: plain partial stores (no global atomics - round-2 lesson).
struct __align__(16) SmC {
  union { unsigned short kt[128 * 64]; float obuf[64 * 64]; } a;  // 16 KB (obuf after loop)
  unsigned short vt[64 * 128];                                    // 16 KB
  union { unsigned short qs[64 * 64]; float zred[4][64]; } c;     // 8 KB (qs dead after qf load)
};

// grid 640: bh = b&31 (XCD-local), t = b>>5 in [0,20): schunk = t&1 (1024 s), l0 = (t>>1)*64
__global__ __launch_bounds__(256, 3) void sparse_attn_mfma(
    const float* __restrict__ q, const unsigned short* __restrict__ kimg,
    const unsigned short* __restrict__ vt_g, const int* __restrict__ topk,
    float* __restrict__ opart, float* __restrict__ zpart) {
  __shared__ SmC sm;
  const int b = blockIdx.x;
  const int bh = b & 31;
  const int t = b >> 5;
  const int schunk = t & 1;
  const int l0 = (t >> 1) * 64;
  const int tid = threadIdx.x;
  const int lane = tid & 63, w = tid >> 6, quad = lane >> 4, l15 = lane & 15;
  const float* qb = q + (size_t)bh * (2048 * 64);
  const unsigned short* kb = kimg + (size_t)bh * (32 * 8192);
  const unsigned short* vtb = vt_g + (size_t)bh * (16 * 8192);
  const int* tkb = topk + bh * U_SEL;

  {  // gather selected q rows -> bf16 * (0.125*log2e), swizzled image in LDS
#pragma unroll
    for (int g = 0; g < 2; ++g) {
      const int ch = g * 256 + tid;
      const int r = ch >> 3, c = ch & 7;
      const int l = l0 + r;
      const int row = (l < U_SEL) ? tkb[l] : tkb[0];
      const float4 f0 = *(const float4*)(qb + (size_t)row * 64 + c * 8);
      const float4 f1 = *(const float4*)(qb + (size_t)row * 64 + c * 8 + 4);
      const float xs[8] = {f0.x, f0.y, f0.z, f0.w, f1.x, f1.y, f1.z, f1.w};
      bf16x8 hv;
#pragma unroll
      for (int j = 0; j < 8; ++j) hv[j] = (short)bf16_rne(xs[j] * SCL_Q);
      *(bf16x8*)&sm.c.qs[(r << 6) + ((c ^ (r & 7)) << 3)] = hv;
    }
  }
  __syncthreads();

  bf16x8 qf[4][2];  // persistent q B-fragments
#pragma unroll
  for (int nt = 0; nt < 4; ++nt)
#pragma unroll
    for (int kc = 0; kc < 2; ++kc)
      qf[nt][kc] = ldfrag_sw(sm.c.qs, nt * 16 + l15, kc * 4 + quad);

  const int sl0 = ((quad & 1) << 5) + l15;  // shfl source lanes for P remap
  const int sl1 = sl0 + 16;
  const bool hi2 = quad >= 2;

  float zrun[4] = {0.f, 0.f, 0.f, 0.f};
  f32x4 oacc[4][4];
#pragma unroll
  for (int a = 0; a < 4; ++a)
#pragma unroll
    for (int b2 = 0; b2 < 4; ++b2) oacc[a][b2] = (f32x4){0.f, 0.f, 0.f, 0.f};

  for (int st = 0; st < 8; ++st) {
    const int tile = schunk * 8 + st;
    __syncthreads();  // prev iter's kt/vt readers done (iter 0: trivial)
    stage_img8(kb + (size_t)(2 * tile) * 8192, sm.a.kt, lane, w);
    stage_img8(kb + (size_t)(2 * tile + 1) * 8192, sm.a.kt + 4096, lane, w);
    stage_img16(vtb + (size_t)tile * 8192, sm.vt, lane, w);
    __syncthreads();  // drain gld_lds

    // K fragments from LDS; S^T = K·q^T : C[m=s][n=qr]
    const int ar0 = w * 32 + l15, ar1 = w * 32 + 16 + l15;
    const bf16x8 a00 = ldfrag_k128(sm.a.kt, ar0, quad);
    const bf16x8 a01 = ldfrag_k128(sm.a.kt, ar0, 4 + quad);
    const bf16x8 a10 = ldfrag_k128(sm.a.kt, ar1, quad);
    const bf16x8 a11 = ldfrag_k128(sm.a.kt, ar1, 4 + quad);

    f32x4 sacc[2][4];
#pragma unroll
    for (int mt = 0; mt < 2; ++mt)
#pragma unroll
      for (int nt = 0; nt < 4; ++nt) {
        f32x4 c = (f32x4){0.f, 0.f, 0.f, 0.f};
        c = __builtin_amdgcn_mfma_f32_16x16x32_bf16(mt ? a10 : a00, qf[nt][0], c, 0, 0, 0);
        c = __builtin_amdgcn_mfma_f32_16x16x32_bf16(mt ? a11 : a01, qf[nt][1], c, 0, 0, 0);
        sacc[mt][nt] = c;
      }

    // p = 2^t; pack to bf16 pairs (word k holds s-pair {base+2k, base+2k+1})
    int wd[4][4];
#pragma unroll
    for (int nt = 0; nt < 4; ++nt) {
      const float p0 = exp2f(sacc[0][nt][0]), p1 = exp2f(sacc[0][nt][1]);
      const float p2 = exp2f(sacc[0][nt][2]), p3 = exp2f(sacc[0][nt][3]);
      const float p4 = exp2f(sacc[1][nt][0]), p5 = exp2f(sacc[1][nt][1]);
      const float p6 = exp2f(sacc[1][nt][2]), p7 = exp2f(sacc[1][nt][3]);
      zrun[nt] += (p0 + p1 + p2 + p3) + (p4 + p5 + p6 + p7);
      wd[nt][0] = cvt_pk_bf16(p0, p1);
      wd[nt][1] = cvt_pk_bf16(p2, p3);
      wd[nt][2] = cvt_pk_bf16(p4, p5);
      wd[nt][3] = cvt_pk_bf16(p6, p7);
    }

    // V fragments from LDS
    bf16x8 vbf[4];
#pragma unroll
    for (int dt = 0; dt < 4; ++dt) {
      const int d = dt * 16 + l15;
      vbf[dt] = *(const bf16x8*)&sm.vt[(d << 7) + (((w * 4 + quad) ^ l15) << 3)];
    }

    // PV: in-register P remap via shfl, then O[qr][d] += P[qr][s]·V[s][d]
#pragma unroll
    for (int mtq = 0; mtq < 4; ++mtq) {
      const int a0 = __shfl(wd[mtq][0], sl0), b0 = __shfl(wd[mtq][2], sl0);
      const int a1 = __shfl(wd[mtq][1], sl0), b1 = __shfl(wd[mtq][3], sl0);
      const int a2 = __shfl(wd[mtq][0], sl1), b2 = __shfl(wd[mtq][2], sl1);
      const int a3 = __shfl(wd[mtq][1], sl1), b3 = __shfl(wd[mtq][3], sl1);
      i32x4 pw;
      pw[0] = hi2 ? b0 : a0;
      pw[1] = hi2 ? b1 : a1;
      pw[2] = hi2 ? b2 : a2;
      pw[3] = hi2 ? b3 : a3;
      const bf16x8 pa = __builtin_bit_cast(bf16x8, pw);
#pragma unroll
      for (int dt = 0; dt < 4; ++dt)
        oacc[mtq][dt] = __builtin_amdgcn_mfma_f32_16x16x32_bf16(pa, vbf[dt], oacc[mtq][dt], 0, 0, 0);
    }
  }

  __syncthreads();  // loop done; kt/vt/qs all dead

  // Z: reduce over quads in-wave, stash per-wave rows (zred unions over dead qs)
#pragma unroll
  for (int nt = 0; nt < 4; ++nt) {
    float z = zrun[nt];
    z += __shfl_xor(z, 16);
    z += __shfl_xor(z, 32);
    if (quad == 0) sm.c.zred[w][nt * 16 + l15] = z;
  }
  for (int i = tid; i < 64 * 64; i += 256) sm.a.obuf[i] = 0.f;
  __syncthreads();
#pragma unroll
  for (int mtq = 0; mtq < 4; ++mtq)
#pragma unroll
    for (int r = 0; r < 4; ++r) {
      const int qr = mtq * 16 + quad * 4 + r;
#pragma unroll
      for (int dt = 0; dt < 4; ++dt)
        atomicAdd(&sm.a.obuf[qr * 64 + dt * 16 + l15], oacc[mtq][dt][r]);
    }
  __syncthreads();
  {  // plain coalesced partial stores (no global atomics)
    const int qr = tid >> 2, seg = tid & 3;
    float* op = &opart[(((size_t)(bh * 2 + schunk) * 640) + l0 + qr) * 64 + seg * 16];
    const float* ob = &sm.a.obuf[qr * 64 + seg * 16];
#pragma unroll
    for (int j = 0; j < 4; ++j) *(float4*)&op[j * 4] = *(const float4*)&ob[j * 4];
    if (tid < 64) {
      const float Zt = sm.c.zred[0][tid] + sm.c.zred[1][tid] + sm.c.zred[2][tid] + sm.c.zred[3][tid];
      zpart[(bh * 2 + schunk) * 640 + l0 + tid] = Zt;
    }
  }
}

// ====== Phase D: merge 2 schunk partials, normalize, scatter to out ======
__global__ __launch_bounds__(256) void normalize_kernel(
    const int* __restrict__ topk, const float* __restrict__ zpart,
    const float* __restrict__ opart, float* __restrict__ out) {
  const int b = blockIdx.x;  // 320
  const int bh = b & 31;
  const int l0 = (b >> 5) * 64;
  const int tid = threadIdx.x;
  const int qr = tid >> 2, seg = tid & 3;
  const int l = l0 + qr;
  if (l >= U_SEL) return;
  const int row = topk[bh * U_SEL + l];
  const float Z = zpart[(bh * 2 + 0) * 640 + l] + zpart[(bh * 2 + 1) * 640 + l];
  const float inv = 1.0f / Z;
  float* op = &out[((size_t)bh * T_DIM + row) * 64 + seg * 16];
#pragma unroll
  for (int j = 0; j < 4; ++j) {
    const float4 p0 = *(const float4*)&opart[(((size_t)(bh * 2 + 0) * 640) + l) * 64 + seg * 16 + j * 4];
    const float4 p1 = *(const float4*)&opart[(((size_t)(bh * 2 + 1) * 640) + l) * 64 + seg * 16 + j * 4];
    float4 o;
    o.x = (p0.x + p1.x) * inv;
    o.y = (p0.y + p1.y) * inv;
    o.z = (p0.z + p1.z) * inv;
    o.w = (p0.w + p1.w) * inv;
    *(float4*)&op[j * 4] = o;
  }
}

extern "C" void kernel_launch(void* const* d_in, const int* in_sizes, int n_in,
                              void* d_out, int out_size, void* d_ws, size_t ws_size,
                              hipStream_t stream) {
  const float* q = (const float*)d_in[0];
  const float* k = (const float*)d_in[1];
  const float* v = (const float*)d_in[2];
  float* out = (float*)d_out;
  // workspace: zw 1MB | topk 80KB | zpart 160KB | kimg 16MB | vt 8MB | opart 10.5MB (~36MB)
  char* ws = (char*)d_ws;
  float2* zw = (float2*)ws;                                  // [2][32][2048] float2
  int* topk = (int*)(ws + 1048576);
  float* zpart = (float*)(ws + 1131520);                     // [32][2][640] f32
  unsigned short* kimg = (unsigned short*)(ws + 1310720);    // 32 bh x 32 tiles x 16 KB
  unsigned short* vt_g = (unsigned short*)(ws + 18087936);   // 32 bh x 16 tiles x 16 KB
  float* opart = (float*)(ws + 26476544);                    // [32][2][640][64] f32

  convert_kernel<<<dim3(2048), dim3(256), 0, stream>>>(k, v, kimg, vt_g, out);
  kl_score_mfma<<<dim3(1024), dim3(256), 0, stream>>>(q, kimg, zw);
  topk_kernel<<<dim3(BH_DIM), dim3(1024), 0, stream>>>(zw, topk);
  sparse_attn_mfma<<<dim3(640), dim3(256), 0, stream>>>(q, kimg, vt_g, topk, opart, zpart);
  normalize_kernel<<<dim3(320), dim3(256), 0, stream>>>(topk, zpart, opart, out);
}

// Round 5
// 231.204 us; speedup vs baseline: 2.4648x; 1.1615x over previous
//
#include <hip/hip_runtime.h>
#include <math.h>

#define T_DIM 2048
#define S_DIM 2048
#define D_DIM 64
#define BH_DIM 32
#define U_SEL 614
#define QROWS 80
#define LOG_S_D 7.624618986159398
#define LOG2E_F 1.4426950408889634f
#define LN2_D 0.6931471805599453
#define SCL_Q (0.125f * LOG2E_F)  // q scale folded with log2e: scores in log2 domain

typedef __attribute__((ext_vector_type(8))) short bf16x8;
typedef __attribute__((ext_vector_type(4))) short bf16x4;
typedef __attribute__((ext_vector_type(4))) float f32x4;

__device__ __forceinline__ unsigned short bf16_rne(float x) {
  unsigned u = __float_as_uint(x);
  u += 0x7FFF + ((u >> 16) & 1);
  return (unsigned short)(u >> 16);
}
__device__ __forceinline__ float bf16_to_f(unsigned short h) {
  return __uint_as_float(((unsigned)h) << 16);
}

#define GLD_LDS16(g, l)                                                        \
  __builtin_amdgcn_global_load_lds(                                            \
      (const __attribute__((address_space(1))) unsigned int*)(const void*)(g), \
      (__attribute__((address_space(3))) unsigned int*)(void*)(l), 16, 0, 0)

// stage 16 KB image: 4 waves x 4 instr x 64 lanes x 16 B
__device__ __forceinline__ void stage_img16(const unsigned short* __restrict__ g,
                                            unsigned short* l, int lane, int w) {
#pragma unroll
  for (int it = 0; it < 4; ++it) {
    const int chunk = it * 4 + w;
    GLD_LDS16((const char*)g + chunk * 1024 + lane * 16, (char*)l + chunk * 1024);
  }
}
// stage 8 KB image: 4 waves x 2 instr
__device__ __forceinline__ void stage_img8(const unsigned short* __restrict__ g,
                                           unsigned short* l, int lane, int w) {
#pragma unroll
  for (int it = 0; it < 2; ++it) {
    const int chunk = it * 4 + w;
    GLD_LDS16((const char*)g + chunk * 1024 + lane * 16, (char*)l + chunk * 1024);
  }
}

// swizzled image, 64-wide rows: element (r,d) at r*64 + ((d>>3)^(r&7))*8 + (d&7)
__device__ __forceinline__ bf16x8 ldfrag_sw(const unsigned short* buf, int row, int chunk) {
  return *(const bf16x8*)(buf + (row << 6) + (((chunk) ^ (row & 7)) << 3));
}
// two stacked 64-row images (rows 0..127)
__device__ __forceinline__ bf16x8 ldfrag_k128(const unsigned short* buf, int row, int chunk) {
  return *(const bf16x8*)(buf + ((row >> 6) << 12) + ((row & 63) << 6) +
                          (((chunk) ^ (row & 7)) << 3));
}

// ====== convert: K -> 64-row tiles [hi 8KB | lo 8KB] swizzled; V -> V^T images; zero(out) ======
__global__ __launch_bounds__(256) void convert_kernel(
    const float* __restrict__ kin, const float* __restrict__ vin,
    unsigned short* __restrict__ kimg, unsigned short* __restrict__ vt_g,
    float* __restrict__ out) {
  __shared__ float vld[128][65];
  const int jb = blockIdx.x;
  const int tid = threadIdx.x;
  if (jb < 1024) {  // K: 32 bh x 32 tiles of 64 rows
    const int bh = jb >> 5, tl = jb & 31;
    const float* src = kin + ((size_t)bh * 2048 + tl * 64) * 64;
    unsigned short* dst = kimg + (size_t)(bh * 32 + tl) * 8192;
#pragma unroll
    for (int g = 0; g < 2; ++g) {
      const int flat = g * 256 + tid;  // 512 chunks = 64 rows x 8
      const int r = flat >> 3, c = flat & 7;
      const float4 f0 = *(const float4*)(src + r * 64 + c * 8);
      const float4 f1 = *(const float4*)(src + r * 64 + c * 8 + 4);
      const float xs[8] = {f0.x, f0.y, f0.z, f0.w, f1.x, f1.y, f1.z, f1.w};
      bf16x8 hv, lv;
#pragma unroll
      for (int j = 0; j < 8; ++j) {
        const unsigned short h = bf16_rne(xs[j]);
        hv[j] = (short)h;
        lv[j] = (short)bf16_rne(xs[j] - bf16_to_f(h));
      }
      const int base = (r << 6) + ((c ^ (r & 7)) << 3);
      *(bf16x8*)(dst + base) = hv;
      *(bf16x8*)(dst + 4096 + base) = lv;
    }
  } else if (jb < 1536) {  // V^T: [64 d][128 s] bf16, chunk ^ (d&15)
    const int jv = jb - 1024;
    const int bh = jv >> 4, tl = jv & 15;
    const float* src = vin + ((size_t)bh * 2048 + tl * 128) * 64;
#pragma unroll
    for (int g = 0; g < 8; ++g) {
      const int f = g * 256 + tid;
      const int r = f >> 4, c4 = f & 15;
      const float4 x = *(const float4*)(src + r * 64 + c4 * 4);
      vld[r][c4 * 4 + 0] = x.x;
      vld[r][c4 * 4 + 1] = x.y;
      vld[r][c4 * 4 + 2] = x.z;
      vld[r][c4 * 4 + 3] = x.w;
    }
    __syncthreads();
    unsigned short* dst = vt_g + (size_t)(bh * 16 + tl) * 8192;
#pragma unroll
    for (int g = 0; g < 4; ++g) {
      const int oc = g * 256 + tid;
      const int d = oc >> 4, cc = oc & 15;
      bf16x8 hv;
#pragma unroll
      for (int j = 0; j < 8; ++j) hv[j] = (short)bf16_rne(vld[cc * 8 + j][d]);
      *(bf16x8*)(dst + (d << 7) + (((cc ^ (d & 15))) << 3)) = hv;
    }
  } else {  // zero d_out: 512 blocks x 2048 float4
    float4* o4 = (float4*)out;
    const size_t b = (size_t)(jb - 1536);
#pragma unroll
    for (int g = 0; g < 8; ++g)
      o4[b * 2048 + g * 256 + tid] = make_float4(0.f, 0.f, 0.f, 0.f);
  }
}

// ====== Phase A: partial (Z,W) per (t-row, s-half), bf16x3 MFMA, BK=64 dbuf ======
// grid 1024: bh = b&31 (XCD-local), ttile = (b>>5)&15, shalf = b>>9
__global__ __launch_bounds__(256, 4) void kl_score_mfma(
    const float* __restrict__ q, const unsigned short* __restrict__ kimg,
    float2* __restrict__ zw) {
  __shared__ __align__(16) unsigned short lbuf[2][8192];  // 2 x 16 KB
  const int b = blockIdx.x;
  const int bh = b & 31;
  const int t0 = ((b >> 5) & 15) * 128;
  const int shalf = b >> 9;
  const int tid = threadIdx.x;
  const int lane = tid & 63, w = tid >> 6, quad = lane >> 4, l15 = lane & 15;
  const float* qb = q + (size_t)bh * (2048 * 64) + (size_t)t0 * 64;
  const unsigned short* kb = kimg + (size_t)bh * (32 * 8192);
  const int tg0 = shalf * 16;

  {  // q tile -> hi image in lbuf[0], lo image in lbuf[1] (scaled by 0.125*log2e)
#pragma unroll
    for (int g = 0; g < 4; ++g) {
      const int flat = g * 256 + tid;  // 1024 chunks = 128 rows x 8
      const int r = flat >> 3, c = flat & 7;
      const float4 f0 = *(const float4*)(qb + r * 64 + c * 8);
      const float4 f1 = *(const float4*)(qb + r * 64 + c * 8 + 4);
      const float xs[8] = {f0.x, f0.y, f0.z, f0.w, f1.x, f1.y, f1.z, f1.w};
      bf16x8 hv, lv;
#pragma unroll
      for (int j = 0; j < 8; ++j) {
        const float x = xs[j] * SCL_Q;
        const unsigned short h = bf16_rne(x);
        hv[j] = (short)h;
        lv[j] = (short)bf16_rne(x - bf16_to_f(h));
      }
      const int r2 = r & 63, hi2 = r >> 6;  // rows 0-63 -> lbuf[x][0..4096), 64-127 -> +4096
      const int base = hi2 * 4096 + (r2 << 6) + ((c ^ (r2 & 7)) << 3);
      *(bf16x8*)(&lbuf[0][0] + base) = hv;
      *(bf16x8*)(&lbuf[1][0] + base) = lv;
    }
  }
  __syncthreads();

  bf16x8 ah[2][2], al[2][2];  // persistent q A-fragments (wave w: t-rows w*32..w*32+31)
#pragma unroll
  for (int rt = 0; rt < 2; ++rt) {
    const int row = w * 32 + rt * 16 + l15;
#pragma unroll
    for (int kc = 0; kc < 2; ++kc) {
      ah[rt][kc] = ldfrag_k128(&lbuf[0][0], row, kc * 4 + quad);
      al[rt][kc] = ldfrag_k128(&lbuf[1][0], row, kc * 4 + quad);
    }
  }
  __syncthreads();

  stage_img16(kb + (size_t)tg0 * 8192, &lbuf[0][0], lane, w);
  __syncthreads();  // drain tile 0

  float Zf[8], Wf[8];
#pragma unroll
  for (int i = 0; i < 8; ++i) { Zf[i] = 0.f; Wf[i] = 0.f; }

  for (int t = 0; t < 16; ++t) {
    if (t < 15)
      stage_img16(kb + (size_t)(tg0 + t + 1) * 8192, &lbuf[(t + 1) & 1][0], lane, w);
    const unsigned short* cb = &lbuf[t & 1][0];  // [hi 4096 | lo 4096] elems, 64 rows

    f32x4 acc[2][4];
#pragma unroll
    for (int rt = 0; rt < 2; ++rt)
#pragma unroll
      for (int ct = 0; ct < 4; ++ct) acc[rt][ct] = (f32x4){0.f, 0.f, 0.f, 0.f};

#pragma unroll
    for (int ct = 0; ct < 4; ++ct) {
      const int srow = ct * 16 + l15;
      const bf16x8 bh0 = ldfrag_sw(cb, srow, quad);
      const bf16x8 bl0 = ldfrag_sw(cb + 4096, srow, quad);
      const bf16x8 bh1 = ldfrag_sw(cb, srow, 4 + quad);
      const bf16x8 bl1 = ldfrag_sw(cb + 4096, srow, 4 + quad);
#pragma unroll
      for (int rt = 0; rt < 2; ++rt) {
        f32x4 c = acc[rt][ct];
        c = __builtin_amdgcn_mfma_f32_16x16x32_bf16(ah[rt][0], bh0, c, 0, 0, 0);
        c = __builtin_amdgcn_mfma_f32_16x16x32_bf16(al[rt][0], bh0, c, 0, 0, 0);
        c = __builtin_amdgcn_mfma_f32_16x16x32_bf16(ah[rt][0], bl0, c, 0, 0, 0);
        c = __builtin_amdgcn_mfma_f32_16x16x32_bf16(ah[rt][1], bh1, c, 0, 0, 0);
        c = __builtin_amdgcn_mfma_f32_16x16x32_bf16(al[rt][1], bh1, c, 0, 0, 0);
        c = __builtin_amdgcn_mfma_f32_16x16x32_bf16(ah[rt][1], bl1, c, 0, 0, 0);
        acc[rt][ct] = c;
      }
    }

    // no-max epilogue (log2 domain): e = 2^t, W2 += e*t  (fp32 accumulators)
#pragma unroll
    for (int rt = 0; rt < 2; ++rt)
#pragma unroll
      for (int r = 0; r < 4; ++r) {
        float zp = 0.f, wp = 0.f;
#pragma unroll
        for (int ct = 0; ct < 4; ++ct) {
          const float tt = acc[rt][ct][r];
          const float e = exp2f(tt);
          zp += e;
          wp = fmaf(e, tt, wp);
        }
        Zf[rt * 4 + r] += zp;
        Wf[rt * 4 + r] += wp;
      }
    __syncthreads();  // readers done; drains prefetch of t+1
  }

#pragma unroll
  for (int i = 0; i < 8; ++i) {
    float Zt = Zf[i], Wt = Wf[i];
#pragma unroll
    for (int mask = 1; mask <= 8; mask <<= 1) {
      Zt += __shfl_xor(Zt, mask);
      Wt += __shfl_xor(Wt, mask);
    }
    if (l15 == 0) {
      const int row = t0 + w * 32 + (i >> 2) * 16 + quad * 4 + (i & 3);
      zw[((size_t)shalf * 32 + bh) * 2048 + row] = make_float2(Zt, Wt);
    }
  }
}

// ====== Phase B: kl from (Z,W) halves + exact top-614, bitonic, 1024 threads ======
__global__ __launch_bounds__(1024) void topk_kernel(const float2* __restrict__ zw,
                                                    int* __restrict__ topk) {
  __shared__ float sv[2048];
  __shared__ int si[2048];
  const int bh = blockIdx.x;
  const int tid = threadIdx.x;
  for (int i = tid; i < 2048; i += 1024) {
    const float2 a = zw[(size_t)bh * 2048 + i];
    const float2 c = zw[(size_t)(32 + bh) * 2048 + i];
    const double Z = (double)a.x + (double)c.x;
    const double W = (double)a.y + (double)c.y;
    sv[i] = (float)(LN2_D * (W / Z) - log(Z) + LOG_S_D);
    si[i] = i;
  }
  __syncthreads();
  for (int kk = 2; kk <= 2048; kk <<= 1) {
    for (int j = kk >> 1; j > 0; j >>= 1) {
      const int p = tid;
      const int i = ((p & ~(j - 1)) << 1) | (p & (j - 1));
      const int pr = i | j;
      const float v1 = sv[i], v2 = sv[pr];
      const int i1 = si[i], i2 = si[pr];
      const bool beforePI = (v2 > v1) || (v2 == v1 && i2 < i1);
      const bool dirDesc = ((i & kk) == 0);
      const bool doSwap = dirDesc ? beforePI : !beforePI;
      if (doSwap) { sv[i] = v2; sv[pr] = v1; si[i] = i2; si[pr] = i1; }
      __syncthreads();
    }
  }
  for (int i = tid; i < U_SEL; i += 1024) topk[bh * U_SEL + i] = si[i];
}

// ====== Phase C: bf16 MFMA attention, 256 blocks = EXACTLY 1 block/CU ======
// Round-4 lesson: all variants are bound by per-block serial time x worst-CU
// block count, not by occupancy or stage latency. Fix: perfectly balanced grid
// (8 l-tiles x 80 rows x 32 bh = 256 blocks), full 2048-s loop per block,
// ps-LDS P path (empirically faster than shfl storm), K+V double-buffered
// (LDS is free at 1 block/CU), ONE barrier per iteration, setprio on MFMA.
struct __align__(16) SmC {
  union { unsigned short kt[2][8192]; float obuf[QROWS * 64]; } a;  // 32 KB (obuf after loop)
  union { unsigned short vt[2][8192]; float zred[4][QROWS]; } b;    // 32 KB (zred after loop)
  unsigned short qs[QROWS * 64];                                    // 10 KB
  unsigned short ps[4][QROWS * 40];                                 // 25.6 KB
};

// grid 256: bh = b&31 (XCD-affine: K/V of 4 bh = 3MB per XCD L2), lt = b>>5
__global__ __launch_bounds__(256, 1) void sparse_attn_mfma(
    const float* __restrict__ q, const unsigned short* __restrict__ kimg,
    const unsigned short* __restrict__ vt_g, const int* __restrict__ topk,
    float* __restrict__ out) {
  __shared__ SmC sm;
  const int b = blockIdx.x;
  const int bh = b & 31;
  const int l0 = (b >> 5) * QROWS;
  const int tid = threadIdx.x;
  const int lane = tid & 63, w = tid >> 6, quad = lane >> 4, l15 = lane & 15;
  const float* qb = q + (size_t)bh * (2048 * 64);
  const unsigned short* kb = kimg + (size_t)bh * (32 * 8192);
  const unsigned short* vtb = vt_g + (size_t)bh * (16 * 8192);
  const int* tkb = topk + bh * U_SEL;

  {  // gather 80 selected q rows -> bf16 * (0.125*log2e), swizzled image in LDS
#pragma unroll
    for (int g = 0; g < 3; ++g) {
      const int ch = g * 256 + tid;
      if (ch < QROWS * 8) {
        const int r = ch >> 3, c = ch & 7;
        const int l = l0 + r;
        const int row = (l < U_SEL) ? tkb[l] : tkb[0];
        const float4 f0 = *(const float4*)(qb + (size_t)row * 64 + c * 8);
        const float4 f1 = *(const float4*)(qb + (size_t)row * 64 + c * 8 + 4);
        const float xs[8] = {f0.x, f0.y, f0.z, f0.w, f1.x, f1.y, f1.z, f1.w};
        bf16x8 hv;
#pragma unroll
        for (int j = 0; j < 8; ++j) hv[j] = (short)bf16_rne(xs[j] * SCL_Q);
        *(bf16x8*)&sm.qs[(r << 6) + ((c ^ (r & 7)) << 3)] = hv;
      }
    }
  }
  // prologue: stage tile 0 (K-hi 16 KB + V^T 16 KB) into buffer 0
  stage_img8(kb, sm.a.kt[0], lane, w);
  stage_img8(kb + 8192, sm.a.kt[0] + 4096, lane, w);
  stage_img16(vtb, sm.b.vt[0], lane, w);
  __syncthreads();  // qs ready + tile 0 drained

  bf16x8 qf[5][2];  // persistent q B-fragments (80 rows -> 5 nt tiles)
#pragma unroll
  for (int nt = 0; nt < 5; ++nt)
#pragma unroll
    for (int kc = 0; kc < 2; ++kc)
      qf[nt][kc] = ldfrag_sw(sm.qs, nt * 16 + l15, kc * 4 + quad);

  float zrun[5] = {0.f, 0.f, 0.f, 0.f, 0.f};
  f32x4 oacc[5][4];
#pragma unroll
  for (int a = 0; a < 5; ++a)
#pragma unroll
    for (int b2 = 0; b2 < 4; ++b2) oacc[a][b2] = (f32x4){0.f, 0.f, 0.f, 0.f};

  for (int st = 0; st < 16; ++st) {
    // prefetch tile st+1 into the other buffer; loads fly during compute,
    // drained by the single end-of-iteration __syncthreads.
    if (st < 15) {
      unsigned short* kd = sm.a.kt[(st + 1) & 1];
      unsigned short* vd = sm.b.vt[(st + 1) & 1];
      stage_img8(kb + (size_t)(2 * st + 2) * 8192, kd, lane, w);
      stage_img8(kb + (size_t)(2 * st + 3) * 8192, kd + 4096, lane, w);
      stage_img16(vtb + (size_t)(st + 1) * 8192, vd, lane, w);
    }
    const unsigned short* kcur = sm.a.kt[st & 1];
    const unsigned short* vcur = sm.b.vt[st & 1];

    // S^T = K·q^T : C[m=s][n=qr]; wave w owns s in [w*32, w*32+32)
    const int ar0 = w * 32 + l15, ar1 = w * 32 + 16 + l15;
    const bf16x8 a00 = ldfrag_k128(kcur, ar0, quad);
    const bf16x8 a01 = ldfrag_k128(kcur, ar0, 4 + quad);
    const bf16x8 a10 = ldfrag_k128(kcur, ar1, quad);
    const bf16x8 a11 = ldfrag_k128(kcur, ar1, 4 + quad);

    f32x4 sacc[2][5];
    __builtin_amdgcn_s_setprio(1);
#pragma unroll
    for (int mt = 0; mt < 2; ++mt)
#pragma unroll
      for (int nt = 0; nt < 5; ++nt) {
        f32x4 c = (f32x4){0.f, 0.f, 0.f, 0.f};
        c = __builtin_amdgcn_mfma_f32_16x16x32_bf16(mt ? a10 : a00, qf[nt][0], c, 0, 0, 0);
        c = __builtin_amdgcn_mfma_f32_16x16x32_bf16(mt ? a11 : a01, qf[nt][1], c, 0, 0, 0);
        sacc[mt][nt] = c;
      }
    __builtin_amdgcn_s_setprio(0);

    // no-max: p = 2^t; wave-local ps round-trip (no barrier needed)
#pragma unroll
    for (int nt = 0; nt < 5; ++nt) {
      float zl = 0.f;
#pragma unroll
      for (int mt = 0; mt < 2; ++mt) {
        bf16x4 pw;
#pragma unroll
        for (int r = 0; r < 4; ++r) {
          const float p = exp2f(sacc[mt][nt][r]);
          zl += p;
          pw[r] = (short)bf16_rne(p);
        }
        *(bf16x4*)&sm.ps[w][(nt * 16 + l15) * 40 + mt * 16 + quad * 4] = pw;
      }
      zrun[nt] += zl;
    }

    // V fragments from LDS
    bf16x8 vbf[4];
#pragma unroll
    for (int dt = 0; dt < 4; ++dt) {
      const int d = dt * 16 + l15;
      vbf[dt] = *(const bf16x8*)&vcur[(d << 7) + (((w * 4 + quad) ^ l15) << 3)];
    }

    // PV: O[qr][d] += P[qr][s]·V[s][d]
    __builtin_amdgcn_s_setprio(1);
#pragma unroll
    for (int mtq = 0; mtq < 5; ++mtq) {
      const bf16x8 pa = *(const bf16x8*)&sm.ps[w][(mtq * 16 + l15) * 40 + quad * 8];
#pragma unroll
      for (int dt = 0; dt < 4; ++dt)
        oacc[mtq][dt] = __builtin_amdgcn_mfma_f32_16x16x32_bf16(pa, vbf[dt], oacc[mtq][dt], 0, 0, 0);
    }
    __builtin_amdgcn_s_setprio(0);
    __syncthreads();  // readers of buf[st&1] done + drains prefetch of st+1
  }

  // Z: reduce over quads in-wave, stash per-wave rows (zred unions dead vt)
#pragma unroll
  for (int nt = 0; nt < 5; ++nt) {
    float z = zrun[nt];
    z += __shfl_xor(z, 16);
    z += __shfl_xor(z, 32);
    if (quad == 0) sm.b.zred[w][nt * 16 + l15] = z;
  }
  for (int i = tid; i < QROWS * 64; i += 256) sm.a.obuf[i] = 0.f;
  __syncthreads();
#pragma unroll
  for (int mtq = 0; mtq < 5; ++mtq)
#pragma unroll
    for (int r = 0; r < 4; ++r) {
      const int qr = mtq * 16 + quad * 4 + r;
#pragma unroll
      for (int dt = 0; dt < 4; ++dt)
        atomicAdd(&sm.a.obuf[qr * 64 + dt * 16 + l15], oacc[mtq][dt][r]);
    }
  __syncthreads();
  {  // normalized direct store: 80 rows x 4 segs = 320 work items
#pragma unroll
    for (int it = 0; it < 2; ++it) {
      const int tt = it * 256 + tid;
      if (tt < QROWS * 4) {
        const int qr = tt >> 2, seg = tt & 3;
        const int l = l0 + qr;
        if (l < U_SEL) {
          const float Zt = sm.b.zred[0][qr] + sm.b.zred[1][qr] +
                           sm.b.zred[2][qr] + sm.b.zred[3][qr];
          const float inv = 1.0f / Zt;
          const int row = tkb[l];
          float* op = &out[((size_t)bh * T_DIM + row) * 64 + seg * 16];
          const float* ob = &sm.a.obuf[qr * 64 + seg * 16];
#pragma unroll
          for (int j = 0; j < 4; ++j) {
            float4 o;
            o.x = ob[j * 4 + 0] * inv;
            o.y = ob[j * 4 + 1] * inv;
            o.z = ob[j * 4 + 2] * inv;
            o.w = ob[j * 4 + 3] * inv;
            *(float4*)&op[j * 4] = o;
          }
        }
      }
    }
  }
}

extern "C" void kernel_launch(void* const* d_in, const int* in_sizes, int n_in,
                              void* d_out, int out_size, void* d_ws, size_t ws_size,
                              hipStream_t stream) {
  const float* q = (const float*)d_in[0];
  const float* k = (const float*)d_in[1];
  const float* v = (const float*)d_in[2];
  float* out = (float*)d_out;
  // workspace: zw 1 MB | topk 78 KB | kimg 16 MB | vt 8 MB  (~25.3 MB)
  char* ws = (char*)d_ws;
  float2* zw = (float2*)ws;                                  // [2][32][2048] float2
  int* topk = (int*)(ws + 1048576);
  unsigned short* kimg = (unsigned short*)(ws + 1310720);    // 32 bh x 32 tiles x 16 KB
  unsigned short* vt_g = (unsigned short*)(ws + 18087936);   // 32 bh x 16 tiles x 16 KB

  convert_kernel<<<dim3(2048), dim3(256), 0, stream>>>(k, v, kimg, vt_g, out);
  kl_score_mfma<<<dim3(1024), dim3(256), 0, stream>>>(q, kimg, zw);
  topk_kernel<<<dim3(BH_DIM), dim3(1024), 0, stream>>>(zw, topk);
  sparse_attn_mfma<<<dim3(256), dim3(256), 0, stream>>>(q, kimg, vt_g, topk, out);
}